// Round 14
// baseline (755.260 us; speedup 1.0000x reference)
//
#include <hip/hip_runtime.h>
#include <hip/hip_bf16.h>

// GridTransformerBlock on MI355X (gfx950).
// B=8, S=16384, E=256, FF=1024, H=W=128, G=16 -> 512 windows of 256x256.
//
// Path A (ws >= 203 MB): qkv_win -> attn_hyb2 (Q from image) -> ffn_ln3d
//   (sliced FFN, LDS-staged Y, DOUBLE-BUFFERED h: 1 barrier/slice instead
//    of 2; hazard audit in kernel comment. Math identical to R13's 401us
//    ffn_ln3s which PASSED.)
// Path B (ws >= 136 MB): kv_win -> attn_hyb (proven R3/R9) -> ffn_ln
// Path C: monolithic attn_win + ffn_ln (proven baseline)
//
// Ledger: __launch_bounds__ min-waves>=4 => silent corruption (R6 bisect;
// R13 confirms the sliced FFN structure itself is sound at (512,2));
// 1024-thread blocks force VGPR=64 (R7/R8); multi-block/CU residency never
// materializes (R6/R11). ffn_ln's VGPR=116 rematerialization drag fixed by
// LDS-staged tile (R13: 480->401us). Only (512,2)/(256,2) shapes used.

typedef __bf16 bf16x8 __attribute__((ext_vector_type(8)));
typedef float  f32x4  __attribute__((ext_vector_type(4)));
typedef unsigned short us16;
typedef us16 us16x8 __attribute__((ext_vector_type(8)));
typedef us16 us16x4 __attribute__((ext_vector_type(4)));
typedef us16 us16x2 __attribute__((ext_vector_type(2)));

#define DI static __device__ __forceinline__

DI us16 f2b(float f){ __bf16 h = (__bf16)f; return __builtin_bit_cast(us16, h); }

DI bf16x8 cvt8(f32x4 a, f32x4 b){
  bf16x8 r;
  r[0]=(__bf16)a[0]; r[1]=(__bf16)a[1]; r[2]=(__bf16)a[2]; r[3]=(__bf16)a[3];
  r[4]=(__bf16)b[0]; r[5]=(__bf16)b[1]; r[6]=(__bf16)b[2]; r[7]=(__bf16)b[3];
  return r;
}
DI bf16x8 ld8(const us16* p){
  us16x8 v = *(const us16x8*)p;
  return __builtin_bit_cast(bf16x8, v);
}
DI f32x4 mfma16(bf16x8 a, bf16x8 b, f32x4 c){
  return __builtin_amdgcn_mfma_f32_16x16x32_bf16(a, b, c, 0, 0, 0);
}

// XOR-chunk-swizzled [32][256] bf16 tile, pitch 512 B (chunk = 16B of 8 bf16).
DI bf16x8 ld_sw8(const char* base, int row, int f0){ // f0 multiple of 8
  return ld8((const us16*)(base + row*512 + ((((f0>>3) ^ (row&7))) << 4)));
}
DI void st_sw1(char* base, int row, int f, us16 v){
  *(us16*)(base + row*512 + ((((f>>3) ^ (row&7))) << 4) + (f&7)*2) = v;
}
DI void st_sw4(char* base, int row, int f0, us16x4 v){ // f0 multiple of 4
  *(us16x4*)(base + row*512 + ((((f0>>3) ^ (row&7))) << 4) + (f0&7)*2) = v;
}

// V^T tile [256 f][32 k] bf16, pitch 64 B, chunk-swizzle c ^= (row>>1)&3 (2-way max).
DI bf16x8 ld_vt(const char* base, int row, int gg){
  return ld8((const us16*)(base + row*64 + (((gg ^ ((row>>1)&3))) << 4)));
}
DI void st_vt(char* base, int row, int col, us16 v){
  int c = col >> 3;
  *(us16*)(base + row*64 + (((c ^ ((row>>1)&3))) << 4) + (col&7)*2) = v;
}

// ---------------- weight prep: bf16 + transpose to [out][in] rows -----------
__global__ void prep_w(const float* __restrict__ src, us16* __restrict__ dst,
                       int R, int C, int cshift){
  int idx = blockIdx.x*256 + threadIdx.x;
  if(idx >= R*C) return;
  int r = idx >> cshift;          // row in src (R x C)
  int c = idx & (C-1);
  dst[(size_t)c*R + r] = f2b(src[idx]);   // dst is C x R
}

// =====================================================================
// K1a: Q/K/V projection (Path A). [PROVEN R10/R12/R13]
// =====================================================================
__global__ __launch_bounds__(256, 2)
void qkv_win(const float* __restrict__ x,
             const us16* __restrict__ WqT, const us16* __restrict__ WkT,
             const us16* __restrict__ WvT,
             const float* __restrict__ bq, const float* __restrict__ bk,
             const float* __restrict__ bv,
             char* __restrict__ Qimg, char* __restrict__ KV)
{
  __shared__ __align__(16) char smem[65536];
  const int tid = threadIdx.x;
  const int wl = tid >> 6, lane = tid & 63, l15 = lane & 15, g = lane >> 4;
  const int blk = blockIdx.x;
  const int hw = blk & 1, tg = (blk>>1)&7, wh = (blk>>4)&7, b = blk>>7;
  const int win = wh*8 + hw*4 + wl;

  {
    const float* xb = x + (size_t)b*4194304 + (size_t)(tg*32)*16384 + wh*2048 + hw*64;
    const int prow = tid >> 4, pc = tid & 15;
    char* abase = smem + (pc>>2)*16384;
    const int f0 = prow*16 + (pc&3)*4;
    for(int t=0; t<32; t++){
      f32x4 v = *(const f32x4*)(xb + (size_t)t*16384 + prow*128 + pc*4);
      us16x4 pk; pk[0]=f2b(v[0]); pk[1]=f2b(v[1]); pk[2]=f2b(v[2]); pk[3]=f2b(v[3]);
      st_sw4(abase, t, f0, pk);
    }
  }
  __syncthreads();
  bf16x8 tA[2][8];
  #pragma unroll
  for(int mi=0; mi<2; mi++)
    #pragma unroll
    for(int kk=0; kk<8; kk++)
      tA[mi][kk] = ld_sw8(smem + wl*16384, mi*16 + l15, kk*32 + g*8);
  __syncthreads();

  char* outb = smem + wl*16384;
  const size_t wslot = (size_t)(b*64 + win);

  // ---- Q ----
  for(int n0=0; n0<16; n0++){
    f32x4 a0 = {0,0,0,0}, a1 = {0,0,0,0};
    const us16* wrow = WqT + (size_t)(n0*16 + l15)*256;
    #pragma unroll
    for(int kk=0; kk<8; kk++){
      bf16x8 wb = ld8(wrow + kk*32 + g*8);
      a0 = mfma16(tA[0][kk], wb, a0);
      a1 = mfma16(tA[1][kk], wb, a1);
    }
    float bias = bq[n0*16 + l15];
    #pragma unroll
    for(int r=0; r<4; r++){
      st_sw1(outb, g*4+r,    n0*16+l15, f2b(a0[r] + bias));
      st_sw1(outb, 16+g*4+r, n0*16+l15, f2b(a1[r] + bias));
    }
  }
  asm volatile("" ::: "memory");
  {
    char* dst = Qimg + (wslot*8 + tg)*16384;
    #pragma unroll
    for(int i=0; i<16; i++)
      *(us16x8*)(dst + i*1024 + lane*16) = *(const us16x8*)(outb + i*1024 + lane*16);
  }
  asm volatile("" ::: "memory");

  // ---- K ----
  for(int n0=0; n0<16; n0++){
    f32x4 a0 = {0,0,0,0}, a1 = {0,0,0,0};
    const us16* wrow = WkT + (size_t)(n0*16 + l15)*256;
    #pragma unroll
    for(int kk=0; kk<8; kk++){
      bf16x8 wb = ld8(wrow + kk*32 + g*8);
      a0 = mfma16(tA[0][kk], wb, a0);
      a1 = mfma16(tA[1][kk], wb, a1);
    }
    float bias = bk[n0*16 + l15];
    #pragma unroll
    for(int r=0; r<4; r++){
      st_sw1(outb, g*4+r,    n0*16+l15, f2b(a0[r] + bias));
      st_sw1(outb, 16+g*4+r, n0*16+l15, f2b(a1[r] + bias));
    }
  }
  asm volatile("" ::: "memory");
  {
    char* dst = KV + wslot*262144 + tg*16384;
    #pragma unroll
    for(int i=0; i<16; i++)
      *(us16x8*)(dst + i*1024 + lane*16) = *(const us16x8*)(outb + i*1024 + lane*16);
  }
  asm volatile("" ::: "memory");

  // ---- V^T ----
  for(int n0=0; n0<16; n0++){
    f32x4 a0 = {0,0,0,0}, a1 = {0,0,0,0};
    const us16* wrow = WvT + (size_t)(n0*16 + l15)*256;
    f32x4 bv4 = *(const f32x4*)(bv + n0*16 + g*4);
    #pragma unroll
    for(int kk=0; kk<8; kk++){
      bf16x8 wa = ld8(wrow + kk*32 + g*8);
      a0 = mfma16(wa, tA[0][kk], a0);
      a1 = mfma16(wa, tA[1][kk], a1);
    }
    #pragma unroll
    for(int r=0; r<4; r++){
      int jr = n0*16 + g*4 + r;
      st_vt(outb, jr, l15,      f2b(a0[r] + bv4[r]));
      st_vt(outb, jr, 16 + l15, f2b(a1[r] + bv4[r]));
    }
  }
  asm volatile("" ::: "memory");
  {
    char* dst = KV + wslot*262144 + 131072 + tg*16384;
    #pragma unroll
    for(int i=0; i<16; i++)
      *(us16x8*)(dst + i*1024 + lane*16) = *(const us16x8*)(outb + i*1024 + lane*16);
  }
}

// =====================================================================
// K1b: K/V-only projection (Path B, PROVEN R3/R9 verbatim)
// =====================================================================
__global__ __launch_bounds__(256, 2)
void kv_win(const float* __restrict__ x,
            const us16* __restrict__ WkT, const us16* __restrict__ WvT,
            const float* __restrict__ bk, const float* __restrict__ bv,
            char* __restrict__ KV)
{
  __shared__ __align__(16) char smem[65536];
  const int tid = threadIdx.x;
  const int wl = tid >> 6, lane = tid & 63, l15 = lane & 15, g = lane >> 4;
  const int blk = blockIdx.x;
  const int hw = blk & 1, tg = (blk>>1)&7, wh = (blk>>4)&7, b = blk>>7;
  const int win = wh*8 + hw*4 + wl;

  {
    const float* xb = x + (size_t)b*4194304 + (size_t)(tg*32)*16384 + wh*2048 + hw*64;
    const int prow = tid >> 4, pc = tid & 15;
    char* abase = smem + (pc>>2)*16384;
    const int f0 = prow*16 + (pc&3)*4;
    for(int t=0; t<32; t++){
      f32x4 v = *(const f32x4*)(xb + (size_t)t*16384 + prow*128 + pc*4);
      us16x4 pk; pk[0]=f2b(v[0]); pk[1]=f2b(v[1]); pk[2]=f2b(v[2]); pk[3]=f2b(v[3]);
      st_sw4(abase, t, f0, pk);
    }
  }
  __syncthreads();
  bf16x8 tA[2][8];
  #pragma unroll
  for(int mi=0; mi<2; mi++)
    #pragma unroll
    for(int kk=0; kk<8; kk++)
      tA[mi][kk] = ld_sw8(smem + wl*16384, mi*16 + l15, kk*32 + g*8);
  __syncthreads();

  char* outb = smem + wl*16384;
  const size_t wslot = (size_t)(b*64 + win);

  for(int n0=0; n0<16; n0++){
    f32x4 a0 = {0,0,0,0}, a1 = {0,0,0,0};
    const us16* wrow = WkT + (size_t)(n0*16 + l15)*256;
    #pragma unroll
    for(int kk=0; kk<8; kk++){
      bf16x8 wb = ld8(wrow + kk*32 + g*8);
      a0 = mfma16(tA[0][kk], wb, a0);
      a1 = mfma16(tA[1][kk], wb, a1);
    }
    float bias = bk[n0*16 + l15];
    #pragma unroll
    for(int r=0; r<4; r++){
      st_sw1(outb, g*4+r,    n0*16+l15, f2b(a0[r] + bias));
      st_sw1(outb, 16+g*4+r, n0*16+l15, f2b(a1[r] + bias));
    }
  }
  asm volatile("" ::: "memory");
  {
    char* dst = KV + wslot*262144 + tg*16384;
    #pragma unroll
    for(int i=0; i<16; i++)
      *(us16x8*)(dst + i*1024 + lane*16) = *(const us16x8*)(outb + i*1024 + lane*16);
  }
  asm volatile("" ::: "memory");

  for(int n0=0; n0<16; n0++){
    f32x4 a0 = {0,0,0,0}, a1 = {0,0,0,0};
    const us16* wrow = WvT + (size_t)(n0*16 + l15)*256;
    f32x4 bv4 = *(const f32x4*)(bv + n0*16 + g*4);
    #pragma unroll
    for(int kk=0; kk<8; kk++){
      bf16x8 wa = ld8(wrow + kk*32 + g*8);
      a0 = mfma16(wa, tA[0][kk], a0);
      a1 = mfma16(wa, tA[1][kk], a1);
    }
    #pragma unroll
    for(int r=0; r<4; r++){
      int jr = n0*16 + g*4 + r;
      st_vt(outb, jr, l15,      f2b(a0[r] + bv4[r]));
      st_vt(outb, jr, 16 + l15, f2b(a1[r] + bv4[r]));
    }
  }
  asm volatile("" ::: "memory");
  {
    char* dst = KV + wslot*262144 + 131072 + tg*16384;
    #pragma unroll
    for(int i=0; i<16; i++)
      *(us16x8*)(dst + i*1024 + lane*16) = *(const us16x8*)(outb + i*1024 + lane*16);
  }
}

// =====================================================================
// K2 shared helpers + core loop [PROVEN R10/R12/R13]
// =====================================================================
DI void load_kv_regs(const char* slot, int kt, us16x8* r, int wid, int lane){
  const char* src = (wid < 4)
      ? slot + (size_t)kt*16384 + wid*4096
      : slot + 131072 + (size_t)kt*16384 + (wid-4)*4096;
  #pragma unroll
  for(int i=0; i<4; i++)
    r[i] = *(const us16x8*)(src + i*1024 + lane*16);
}
DI void write_kv_lds(char* kb, char* vb, const us16x8* r, int wid, int lane){
  char* dst = (wid < 4) ? kb + wid*4096 : vb + (wid-4)*4096;
  #pragma unroll
  for(int i=0; i<4; i++)
    *(us16x8*)(dst + i*1024 + lane*16) = r[i];
}

DI void attn_core_loop(char* smem, us16* Psw, const char* slot,
                       const bf16x8 Qf[2][8], us16x8* stg,
                       const us16* WoT, const float* bo, float* yb,
                       int wid, int lane, int l15, int g, int r0)
{
  us16* Qw = (us16*)(smem) + wid*(32*264);
  float mr0 = -1e30f, mr1 = -1e30f, lr0 = 0.f, lr1 = 0.f;
  f32x4 Ot[16][2];
  const f32x4 zf = {0,0,0,0};
  #pragma unroll
  for(int i=0;i<16;i++){ Ot[i][0]=zf; Ot[i][1]=zf; }
  __syncthreads();               // tile 0 staged

  for(int kt=0; kt<8; kt++){
    char* kb = (kt&1) ? smem + 16384 : smem;
    char* vb = (kt&1) ? smem + 49152 : smem + 32768;
    if(kt < 7) load_kv_regs(slot, kt+1, stg, wid, lane);
    f32x4 st[2][2] = {{zf,zf},{zf,zf}};
    #pragma unroll
    for(int kk=0; kk<8; kk++){
      int f0 = kk*32 + g*8;
      bf16x8 k0 = ld_sw8(kb, l15, f0);
      bf16x8 k1 = ld_sw8(kb, 16 + l15, f0);
      st[0][0] = mfma16(k0, Qf[0][kk], st[0][0]);
      st[0][1] = mfma16(k0, Qf[1][kk], st[0][1]);
      st[1][0] = mfma16(k1, Qf[0][kk], st[1][0]);
      st[1][1] = mfma16(k1, Qf[1][kk], st[1][1]);
    }
    #pragma unroll
    for(int mi=0; mi<2; mi++)
      #pragma unroll
      for(int qn=0; qn<2; qn++)
        #pragma unroll
        for(int r=0; r<4; r++) st[mi][qn][r] *= 0.0625f;
    float tm0 = st[0][0][0], tm1 = st[0][1][0];
    #pragma unroll
    for(int mi=0; mi<2; mi++)
      #pragma unroll
      for(int r=0; r<4; r++){
        tm0 = fmaxf(tm0, st[mi][0][r]);
        tm1 = fmaxf(tm1, st[mi][1][r]);
      }
    tm0 = fmaxf(tm0, __shfl_xor(tm0, 16)); tm0 = fmaxf(tm0, __shfl_xor(tm0, 32));
    tm1 = fmaxf(tm1, __shfl_xor(tm1, 16)); tm1 = fmaxf(tm1, __shfl_xor(tm1, 32));
    float mn0 = fmaxf(mr0, tm0), mn1 = fmaxf(mr1, tm1);
    float c0 = __expf(mr0 - mn0), c1 = __expf(mr1 - mn1);
    float ts0 = 0.f, ts1 = 0.f;
    #pragma unroll
    for(int mi=0; mi<2; mi++)
      #pragma unroll
      for(int r=0; r<4; r++){
        float p0 = __expf(st[mi][0][r] - mn0); st[mi][0][r] = p0; ts0 += p0;
        float p1 = __expf(st[mi][1][r] - mn1); st[mi][1][r] = p1; ts1 += p1;
      }
    ts0 += __shfl_xor(ts0, 16); ts0 += __shfl_xor(ts0, 32);
    ts1 += __shfl_xor(ts1, 16); ts1 += __shfl_xor(ts1, 32);
    lr0 = lr0*c0 + ts0;  lr1 = lr1*c1 + ts1;  mr0 = mn0;  mr1 = mn1;
    #pragma unroll
    for(int i=0;i<16;i++){
      #pragma unroll
      for(int r=0;r<4;r++){ Ot[i][0][r] *= c0; Ot[i][1][r] *= c1; }
    }
    #pragma unroll
    for(int qn=0; qn<2; qn++)
      #pragma unroll
      for(int mi=0; mi<2; mi++)
        #pragma unroll
        for(int rp=0; rp<2; rp++){
          us16x2 pk;
          pk[0] = f2b(st[mi][qn][rp*2]);
          pk[1] = f2b(st[mi][qn][rp*2+1]);
          *(us16x2*)((char*)Psw + (qn*16 + l15)*80 + (mi*16 + g*4 + rp*2)*2) = pk;
        }
    asm volatile("" ::: "memory");
    bf16x8 pb0 = ld8(Psw + l15*40 + g*8);
    bf16x8 pb1 = ld8(Psw + (16 + l15)*40 + g*8);
    #pragma unroll
    for(int fm=0; fm<16; fm++){
      bf16x8 va = ld_vt(vb, fm*16 + l15, g);
      Ot[fm][0] = mfma16(va, pb0, Ot[fm][0]);
      Ot[fm][1] = mfma16(va, pb1, Ot[fm][1]);
    }
    if(kt < 7){
      char* kbn = (kt&1) ? smem : smem + 16384;
      char* vbn = (kt&1) ? smem + 32768 : smem + 49152;
      write_kv_lds(kbn, vbn, stg, wid, lane);
    }
    __syncthreads();
  }

  float inv0 = 1.f/lr0, inv1 = 1.f/lr1;
  #pragma unroll
  for(int fm=0; fm<16; fm++)
    #pragma unroll
    for(int rp=0; rp<2; rp++){
      us16x2 p0, p1;
      p0[0]=f2b(Ot[fm][0][rp*2]*inv0);   p0[1]=f2b(Ot[fm][0][rp*2+1]*inv0);
      p1[0]=f2b(Ot[fm][1][rp*2]*inv1);   p1[1]=f2b(Ot[fm][1][rp*2+1]*inv1);
      *(us16x2*)((char*)Qw + l15*528      + (fm*16 + g*4 + rp*2)*2) = p0;
      *(us16x2*)((char*)Qw + (16+l15)*528 + (fm*16 + g*4 + rp*2)*2) = p1;
    }
  asm volatile("" ::: "memory");
  bf16x8 Of[2][8];
  #pragma unroll
  for(int qm=0; qm<2; qm++)
    #pragma unroll
    for(int kk=0; kk<8; kk++)
      Of[qm][kk] = ld8(Qw + (qm*16 + l15)*264 + kk*32 + g*8);
  for(int n0=0; n0<16; n0++){
    f32x4 a0 = {0,0,0,0}, a1 = {0,0,0,0};
    const us16* wrow = WoT + (size_t)(n0*16 + l15)*256;
    #pragma unroll
    for(int kk=0; kk<8; kk++){
      bf16x8 wb = ld8(wrow + kk*32 + g*8);
      a0 = mfma16(Of[0][kk], wb, a0);
      a1 = mfma16(Of[1][kk], wb, a1);
    }
    float bias = bo[n0*16 + l15];
    #pragma unroll
    for(int r=0; r<4; r++){
      yb[(size_t)(r0 + g*4 + r)*16384      + n0*128 + l15] = a0[r] + bias;
      yb[(size_t)(r0 + 16 + g*4 + r)*16384 + n0*128 + l15] = a1[r] + bias;
    }
  }
}

// ---- Path A: Q from image [PROVEN R10/R12/R13] ----
__global__ __launch_bounds__(512, 2)
void attn_hyb2(const char* __restrict__ Qimg, const char* __restrict__ KV,
               const us16* __restrict__ WoT, const float* __restrict__ bo,
               float* __restrict__ y)
{
  __shared__ __align__(16) char smem[135168];
  const int tid = threadIdx.x, wid = tid>>6, lane = tid&63, l15 = lane&15, g = lane>>4;
  const int blk = blockIdx.x;
  const int b   = blk >> 6;
  const int win = blk & 63;
  const size_t base = (size_t)b*4194304 + (size_t)(win>>3)*2048 + (size_t)(win&7)*16;
  float*       yb = y + base;
  const char*  slot = KV + (size_t)blk*262144;
  const char*  Qt = Qimg + ((size_t)blk*8 + wid)*16384;
  us16* Psw = (us16*)(smem + 65536) + wid*1280;
  const int r0 = wid*32;

  us16x8 stg[4];
  load_kv_regs(slot, 0, stg, wid, lane);

  bf16x8 Qf[2][8];
  #pragma unroll
  for(int qn=0; qn<2; qn++)
    #pragma unroll
    for(int kk=0; kk<8; kk++){
      int row = qn*16 + l15;
      Qf[qn][kk] = ld8((const us16*)(Qt + row*512 + ((((kk*4+g) ^ (l15&7))) << 4)));
    }

  write_kv_lds(smem, smem + 32768, stg, wid, lane);
  attn_core_loop(smem, Psw, slot, Qf, stg, WoT, bo, yb, wid, lane, l15, g, r0);
}

// ---- Path B: proven phase-A Q ----
__global__ __launch_bounds__(512, 2)
void attn_hyb(const float* __restrict__ x,
              const us16* __restrict__ WqT, const float* __restrict__ bq,
              const char* __restrict__ KV,
              const us16* __restrict__ WoT, const float* __restrict__ bo,
              float* __restrict__ y)
{
  __shared__ __align__(16) char smem[135168];
  const int tid = threadIdx.x, wid = tid>>6, lane = tid&63, l15 = lane&15, g = lane>>4;
  const int blk = blockIdx.x;
  const int b   = blk >> 6;
  const int win = blk & 63;
  const size_t base = (size_t)b*4194304 + (size_t)(win>>3)*2048 + (size_t)(win&7)*16;
  const float* xb = x + base;
  float*       yb = y + base;
  const char*  slot = KV + (size_t)blk*262144;

  us16* Qw  = (us16*)(smem) + wid*(32*264);
  us16* Psw = (us16*)(smem + 65536) + wid*1280;
  const int r0 = wid*32;

  us16x8 stg[4];
  load_kv_regs(slot, 0, stg, wid, lane);

  bf16x8 tA[2][8];
  #pragma unroll
  for(int mi=0; mi<2; mi++){
    const float* trow = xb + (size_t)(r0 + mi*16 + l15)*16384;
    #pragma unroll
    for(int kk=0; kk<8; kk++){
      int f0 = kk*32 + g*8;
      const float* p = trow + (f0>>4)*128 + (f0&15);
      tA[mi][kk] = cvt8(*(const f32x4*)p, *(const f32x4*)(p+4));
    }
  }
  for(int n0=0; n0<16; n0++){
    f32x4 a0 = {0,0,0,0}, a1 = {0,0,0,0};
    const us16* wrow = WqT + (size_t)(n0*16 + l15)*256;
    #pragma unroll
    for(int kk=0; kk<8; kk++){
      bf16x8 wb = ld8(wrow + kk*32 + g*8);
      a0 = mfma16(tA[0][kk], wb, a0);
      a1 = mfma16(tA[1][kk], wb, a1);
    }
    float bias = bq[n0*16 + l15];
    #pragma unroll
    for(int r=0; r<4; r++){
      Qw[(g*4+r)*264      + n0*16 + l15] = f2b(a0[r] + bias);
      Qw[(16+g*4+r)*264   + n0*16 + l15] = f2b(a1[r] + bias);
    }
  }
  asm volatile("" ::: "memory");
  bf16x8 Qf[2][8];
  #pragma unroll
  for(int qn=0; qn<2; qn++)
    #pragma unroll
    for(int kk=0; kk<8; kk++)
      Qf[qn][kk] = ld8(Qw + (qn*16 + l15)*264 + kk*32 + g*8);
  __syncthreads();

  write_kv_lds(smem, smem + 32768, stg, wid, lane);
  attn_core_loop(smem, Psw, slot, Qf, stg, WoT, bo, yb, wid, lane, l15, g, r0);
}

// =====================================================================
// K3a: FFN sliced + double-buffered h, (512,2). FF in 4 slices of 256.
// LDS: tile [64][264] @0 (33792) | h0 @33792 | h1 @67584 -> 101376 B.
// Barrier audit:
//  - phase1(q) W(h[q&1]) -> BAR(q) -> phase2(q) R(h[q&1])        [safe]
//  - phase2(q) R(h[q&1]) happens-before BAR(q+1) (program order),
//    phase1(q+2) W(h[q&1]) happens-after BAR(q+1)                [safe]
//  - tile last read phase1(3), fl writes after BAR(3)            [safe]
//  - phase2(3) reads h1 (67584+), fl writes 0..66560 (disjoint)  [safe]
//  - BAR_F before phase-3 fl reads                               [safe]
// Math/order/rounding identical to R13's PASSED ffn_ln3s.
// =====================================================================
__global__ __launch_bounds__(512, 2)
void ffn_ln3d(float* y,   // d_out, in-place
              const us16* __restrict__ W1T, const us16* __restrict__ W2T,
              const float* __restrict__ b1, const float* __restrict__ b2,
              const float* __restrict__ g1, const float* __restrict__ be1,
              const float* __restrict__ g2, const float* __restrict__ be2)
{
  __shared__ __align__(16) char smem[101376];
  us16* tile = (us16*)smem;              // [64][264] bf16 y rows
  float* fl  = (float*)smem;             // overlay after GEMMs: [64][260] f32
  const int tid = threadIdx.x, wid = tid>>6, lane = tid&63, l15 = lane&15, g = lane>>4;
  float* Y = y + (size_t)blockIdx.x*64*256;

  { // stage: 64 canonical rows (1 KB contiguous each) -> bf16 tile (read ONCE)
    #pragma unroll
    for(int rr=0; rr<8; rr++){
      int row = wid*8 + rr;
      f32x4 v = *(const f32x4*)(Y + (size_t)row*256 + lane*4);
      us16x4 pk; pk[0]=f2b(v[0]); pk[1]=f2b(v[1]); pk[2]=f2b(v[2]); pk[3]=f2b(v[3]);
      *(us16x4*)(tile + row*264 + lane*4) = pk;
    }
  }
  __syncthreads();

  const f32x4 zf = {0,0,0,0};
  f32x4 acc2[4][2] = {{zf,zf},{zf,zf},{zf,zf},{zf,zf}};
  for(int q=0; q<4; q++){
    us16* h = (us16*)(smem + 33792 + (q&1)*33792);   // ping-pong buffer
    // phase 1: h = gelu(tile @ W1[:, q*256 .. +255] + b1)
    f32x4 acc[4][2] = {{zf,zf},{zf,zf},{zf,zf},{zf,zf}};
    #pragma unroll
    for(int kk=0; kk<8; kk++){
      int f0 = kk*32 + g*8;
      bf16x8 ya[4];
      #pragma unroll
      for(int mi=0; mi<4; mi++) ya[mi] = ld8(tile + (mi*16 + l15)*264 + f0);
      #pragma unroll
      for(int n=0; n<2; n++){
        bf16x8 wb = ld8(W1T + (size_t)(q*256 + wid*32 + n*16 + l15)*256 + f0);
        #pragma unroll
        for(int mi=0; mi<4; mi++) acc[mi][n] = mfma16(ya[mi], wb, acc[mi][n]);
      }
    }
    #pragma unroll
    for(int n=0; n<2; n++){
      int jl = wid*32 + n*16 + l15;
      float bias = b1[q*256 + jl];
      #pragma unroll
      for(int mi=0; mi<4; mi++)
        #pragma unroll
        for(int r=0; r<4; r++){
          float v = acc[mi][n][r] + bias;
          v = 0.5f*v*(1.f + erff(v*0.70710678118654752f));   // exact GELU
          h[(mi*16 + g*4 + r)*264 + jl] = f2b(v);
        }
    }
    __syncthreads();   // h[q&1] writes visible before its reads
    // phase 2: acc2 += h @ W2[q*256.., :]   (same K-chunk order as monolithic)
    #pragma unroll
    for(int kk=0; kk<8; kk++){
      int f0 = kk*32 + g*8;
      bf16x8 ha[4];
      #pragma unroll
      for(int mi=0; mi<4; mi++) ha[mi] = ld8(h + (mi*16 + l15)*264 + f0);
      #pragma unroll
      for(int n=0; n<2; n++){
        bf16x8 wb = ld8(W2T + (size_t)(wid*32 + n*16 + l15)*1024 + q*256 + f0);
        #pragma unroll
        for(int mi=0; mi<4; mi++) acc2[mi][n] = mfma16(ha[mi], wb, acc2[mi][n]);
      }
    }
    // no barrier: next slice writes the OTHER h buffer; BAR(q+1) separates
    // this slice's h reads from the q+2 overwrite (see audit above).
  }
  // ffn result (f32) -> fl overlay (over tile+h0; phase2(3) reads h1 only)
  #pragma unroll
  for(int n=0; n<2; n++){
    float bias = b2[wid*32 + n*16 + l15];
    #pragma unroll
    for(int mi=0; mi<4; mi++)
      #pragma unroll
      for(int r=0; r<4; r++)
        fl[(mi*16 + g*4 + r)*260 + wid*32 + n*16 + l15] = acc2[mi][n][r] + bias;
  }
  __syncthreads();
  // phase 3: per-row LN(ffn) + residual, then LN again + residual
  f32x4 G1  = *(const f32x4*)(g1  + lane*4);
  f32x4 BE1 = *(const f32x4*)(be1 + lane*4);
  f32x4 G2  = *(const f32x4*)(g2  + lane*4);
  f32x4 BE2 = *(const f32x4*)(be2 + lane*4);
  for(int rr=0; rr<8; rr++){
    int row = wid*8 + rr;
    f32x4 f  = *(const f32x4*)(fl + row*260 + lane*4);
    f32x4 yv = *(const f32x4*)(Y + (size_t)row*256 + lane*4);
    float s  = f[0]+f[1]+f[2]+f[3];
    float s2 = f[0]*f[0]+f[1]*f[1]+f[2]*f[2]+f[3]*f[3];
    #pragma unroll
    for(int m=1; m<=32; m<<=1){ s += __shfl_xor(s, m); s2 += __shfl_xor(s2, m); }
    float mu = s*(1.f/256.f);
    float rs = rsqrtf(fmaxf(s2*(1.f/256.f) - mu*mu, 0.f) + 1e-5f);
    f32x4 y1;
    #pragma unroll
    for(int i=0; i<4; i++) y1[i] = yv[i] + (f[i]-mu)*rs*G1[i] + BE1[i];
    float t1 = y1[0]+y1[1]+y1[2]+y1[3];
    float t2 = y1[0]*y1[0]+y1[1]*y1[1]+y1[2]*y1[2]+y1[3]*y1[3];
    #pragma unroll
    for(int m=1; m<=32; m<<=1){ t1 += __shfl_xor(t1, m); t2 += __shfl_xor(t2, m); }
    float mu2 = t1*(1.f/256.f);
    float rs2 = rsqrtf(fmaxf(t2*(1.f/256.f) - mu2*mu2, 0.f) + 1e-5f);
    f32x4 o;
    #pragma unroll
    for(int i=0; i<4; i++) o[i] = y1[i] + (y1[i]-mu2)*rs2*G2[i] + BE2[i];
    *(f32x4*)(Y + (size_t)row*256 + lane*4) = o;
  }
}

// =====================================================================
// K3b: FFN + 2x LN + residuals (PROVEN 64-row template, Paths B/C)
// =====================================================================
__global__ __launch_bounds__(512, 2)
void ffn_ln(float* y,   // d_out, in-place
            const us16* __restrict__ W1T, const us16* __restrict__ W2T,
            const float* __restrict__ b1, const float* __restrict__ b2,
            const float* __restrict__ g1, const float* __restrict__ be1,
            const float* __restrict__ g2, const float* __restrict__ be2)
{
  __shared__ __align__(16) char smem[132096];
  us16*  h  = (us16*)smem;    // [64][1032] bf16, pitch 2064 B
  float* fl = (float*)smem;   // overlay: [64][260] f32, pitch 1040 B
  const int tid = threadIdx.x, wid = tid>>6, lane = tid&63, l15 = lane&15, g = lane>>4;
  float* Y = y + (size_t)blockIdx.x*64*256;

  bf16x8 ya[4][8];
  #pragma unroll
  for(int mi=0; mi<4; mi++){
    const float* p = Y + (size_t)(mi*16 + l15)*256;
    #pragma unroll
    for(int kk=0; kk<8; kk++){
      int f0 = kk*32 + g*8;
      ya[mi][kk] = cvt8(*(const f32x4*)(p + f0), *(const f32x4*)(p + f0 + 4));
    }
  }
  const f32x4 zf = {0,0,0,0};
  #pragma unroll 2
  for(int n0=0; n0<8; n0++){
    int j = wid*128 + n0*16 + l15;
    f32x4 acc[4] = {zf,zf,zf,zf};
    const us16* wrow = W1T + (size_t)j*256;
    #pragma unroll
    for(int kk=0; kk<8; kk++){
      bf16x8 wb = ld8(wrow + kk*32 + g*8);
      #pragma unroll
      for(int mi=0; mi<4; mi++) acc[mi] = mfma16(ya[mi][kk], wb, acc[mi]);
    }
    float bias = b1[j];
    #pragma unroll
    for(int mi=0; mi<4; mi++)
      #pragma unroll
      for(int r=0; r<4; r++){
        float v = acc[mi][r] + bias;
        v = 0.5f*v*(1.f + erff(v*0.70710678118654752f));   // exact GELU
        h[(mi*16 + g*4 + r)*1032 + j] = f2b(v);
      }
  }
  __syncthreads();
  f32x4 acc2[4][2] = {{zf,zf},{zf,zf},{zf,zf},{zf,zf}};
  #pragma unroll 2
  for(int kk=0; kk<32; kk++){
    int f0 = kk*32 + g*8;
    bf16x8 ha[4];
    #pragma unroll
    for(int mi=0; mi<4; mi++) ha[mi] = ld8(h + (mi*16 + l15)*1032 + f0);
    #pragma unroll
    for(int n=0; n<2; n++){
      bf16x8 wb = ld8(W2T + (size_t)(wid*32 + n*16 + l15)*1024 + f0);
      #pragma unroll
      for(int mi=0; mi<4; mi++) acc2[mi][n] = mfma16(ha[mi], wb, acc2[mi][n]);
    }
  }
  __syncthreads();
  #pragma unroll
  for(int mi=0; mi<4; mi++)
    #pragma unroll
    for(int n=0; n<2; n++){
      float bias = b2[wid*32 + n*16 + l15];
      #pragma unroll
      for(int r=0; r<4; r++)
        fl[(mi*16 + g*4 + r)*260 + wid*32 + n*16 + l15] = acc2[mi][n][r] + bias;
    }
  __syncthreads();
  f32x4 G1  = *(const f32x4*)(g1  + lane*4);
  f32x4 BE1 = *(const f32x4*)(be1 + lane*4);
  f32x4 G2  = *(const f32x4*)(g2  + lane*4);
  f32x4 BE2 = *(const f32x4*)(be2 + lane*4);
  for(int rr=0; rr<8; rr++){
    int row = wid*8 + rr;
    f32x4 f  = *(const f32x4*)(fl + row*260 + lane*4);
    f32x4 yv = *(const f32x4*)(Y + (size_t)row*256 + lane*4);
    float s  = f[0]+f[1]+f[2]+f[3];
    float s2 = f[0]*f[0]+f[1]*f[1]+f[2]*f[2]+f[3]*f[3];
    #pragma unroll
    for(int m=1; m<=32; m<<=1){ s += __shfl_xor(s, m); s2 += __shfl_xor(s2, m); }
    float mu = s*(1.f/256.f);
    float rs = rsqrtf(fmaxf(s2*(1.f/256.f) - mu*mu, 0.f) + 1e-5f);
    f32x4 y1;
    #pragma unroll
    for(int i=0; i<4; i++) y1[i] = yv[i] + (f[i]-mu)*rs*G1[i] + BE1[i];
    float t1 = y1[0]+y1[1]+y1[2]+y1[3];
    float t2 = y1[0]*y1[0]+y1[1]*y1[1]+y1[2]*y1[2]+y1[3]*y1[3];
    #pragma unroll
    for(int m=1; m<=32; m<<=1){ t1 += __shfl_xor(t1, m); t2 += __shfl_xor(t2, m); }
    float mu2 = t1*(1.f/256.f);
    float rs2 = rsqrtf(fmaxf(t2*(1.f/256.f) - mu2*mu2, 0.f) + 1e-5f);
    f32x4 o;
    #pragma unroll
    for(int i=0; i<4; i++) o[i] = y1[i] + (y1[i]-mu2)*rs2*G2[i] + BE2[i];
    *(f32x4*)(Y + (size_t)row*256 + lane*4) = o;
  }
}

// =====================================================================
// FALLBACK: fully proven monolithic attention (used if ws too small)
// =====================================================================
__global__ __launch_bounds__(512, 2)
void attn_win(const float* __restrict__ x,
              const us16* __restrict__ WqT, const us16* __restrict__ WkT,
              const us16* __restrict__ WvT, const us16* __restrict__ WoT,
              const float* __restrict__ bq, const float* __restrict__ bk,
              const float* __restrict__ bv, const float* __restrict__ bo,
              float* __restrict__ y)
{
  __shared__ __align__(16) char smem[135168];
  const int tid = threadIdx.x;
  const int wid = tid >> 6;
  const int lane = tid & 63;
  const int l15 = lane & 15;
  const int g = lane >> 4;

  const int blk = blockIdx.x;
  const int b   = blk >> 6;
  const int win = blk & 63;
  const size_t base = (size_t)b*4194304 + (size_t)(win>>3)*2048 + (size_t)(win&7)*16;
  const float* xb = x + base;
  float*       yb = y + base;

  us16* Qw    = (us16*)(smem) + wid*(32*264);
  char* slabb = smem;
  char* kldsb = smem + 16384;
  us16* Vt    = (us16*)(smem + 32768);
  us16* Psw   = (us16*)(smem + 53248) + wid*1280;

  const int r0 = wid*32;

  bf16x8 tA[2][8];
  #pragma unroll
  for(int mi=0; mi<2; mi++){
    const float* trow = xb + (size_t)(r0 + mi*16 + l15)*16384;
    #pragma unroll
    for(int kk=0; kk<8; kk++){
      int f0 = kk*32 + g*8;
      const float* p = trow + (f0>>4)*128 + (f0&15);
      tA[mi][kk] = cvt8(*(const f32x4*)p, *(const f32x4*)(p+4));
    }
  }
  for(int n0=0; n0<16; n0++){
    f32x4 a0 = {0,0,0,0}, a1 = {0,0,0,0};
    const us16* wrow = WqT + (size_t)(n0*16 + l15)*256;
    #pragma unroll
    for(int kk=0; kk<8; kk++){
      bf16x8 wb = ld8(wrow + kk*32 + g*8);
      a0 = mfma16(tA[0][kk], wb, a0);
      a1 = mfma16(tA[1][kk], wb, a1);
    }
    float bias = bq[n0*16 + l15];
    #pragma unroll
    for(int r=0; r<4; r++){
      Qw[(g*4+r)*264      + n0*16 + l15] = f2b(a0[r] + bias);
      Qw[(16+g*4+r)*264   + n0*16 + l15] = f2b(a1[r] + bias);
    }
  }
  asm volatile("" ::: "memory");
  bf16x8 Qf[2][8];
  #pragma unroll
  for(int qn=0; qn<2; qn++)
    #pragma unroll
    for(int kk=0; kk<8; kk++)
      Qf[qn][kk] = ld8(Qw + (qn*16 + l15)*264 + kk*32 + g*8);
  __syncthreads();

  const float bkv0 = bk[wid*32 + l15], bkv1 = bk[wid*32 + 16 + l15];
  float bvv[2][4];
  #pragma unroll
  for(int m=0; m<2; m++)
    #pragma unroll
    for(int r=0; r<4; r++)
      bvv[m][r] = bv[wid*32 + m*16 + g*4 + r];

  float mr0 = -1e30f, mr1 = -1e30f, lr0 = 0.f, lr1 = 0.f;
  f32x4 Ot[16][2];
  const f32x4 zf = {0,0,0,0};
  #pragma unroll
  for(int i=0;i<16;i++){ Ot[i][0]=zf; Ot[i][1]=zf; }

  for(int kt=0; kt<8; kt++){
    const int kr0 = kt*32;
    {
      int row = tid >> 4, c = tid & 15;
      const float* trow = xb + (size_t)(kr0 + row)*16384;
      #pragma unroll
      for(int j=0; j<4; j++){
        int f0 = (c + 16*j)*4;
        const float* p = trow + (f0>>4)*128 + (f0&15);
        f32x4 v = *(const f32x4*)p;
        us16x4 pk; pk[0]=f2b(v[0]); pk[1]=f2b(v[1]); pk[2]=f2b(v[2]); pk[3]=f2b(v[3]);
        st_sw4(slabb, row, f0, pk);
      }
    }
    __syncthreads();
    {
      f32x4 acc[2][2] = {{zf,zf},{zf,zf}};
      #pragma unroll
      for(int kk=0; kk<8; kk++){
        int f0 = kk*32 + g*8;
        bf16x8 a0 = ld_sw8(slabb, l15, f0);
        bf16x8 a1 = ld_sw8(slabb, 16 + l15, f0);
        #pragma unroll
        for(int n=0; n<2; n++){
          bf16x8 wb = ld8(WkT + (size_t)(wid*32 + n*16 + l15)*256 + f0);
          acc[n][0] = mfma16(a0, wb, acc[n][0]);
          acc[n][1] = mfma16(a1, wb, acc[n][1]);
        }
      }
      #pragma unroll
      for(int n=0; n<2; n++){
        float bias = n ? bkv1 : bkv0;
        #pragma unroll
        for(int r=0; r<4; r++){
          st_sw1(kldsb, g*4+r,      wid*32 + n*16 + l15, f2b(acc[n][0][r] + bias));
          st_sw1(kldsb, 16+g*4+r,   wid*32 + n*16 + l15, f2b(acc[n][1][r] + bias));
        }
      }
    }
    {
      f32x4 acc[2][2] = {{zf,zf},{zf,zf}};
      #pragma unroll
      for(int kk=0; kk<8; kk++){
        int f0 = kk*32 + g*8;
        bf16x8 b0 = ld_sw8(slabb, l15, f0);
        bf16x8 b1 = ld_sw8(slabb, 16 + l15, f0);
        #pragma unroll
        for(int fm=0; fm<2; fm++){
          bf16x8 wa = ld8(WvT + (size_t)(wid*32 + fm*16 + l15)*256 + f0);
          acc[fm][0] = mfma16(wa, b0, acc[fm][0]);
          acc[fm][1] = mfma16(wa, b1, acc[fm][1]);
        }
      }
      #pragma unroll
      for(int fm=0; fm<2; fm++)
        #pragma unroll
        for(int n=0; n<2; n++)
          #pragma unroll
          for(int r=0; r<4; r++){
            int f = wid*32 + fm*16 + g*4 + r;
            Vt[f*40 + n*16 + l15] = f2b(acc[fm][n][r] + bvv[fm][r]);
          }
    }
    __syncthreads();
    f32x4 st[2][2] = {{zf,zf},{zf,zf}};
    #pragma unroll
    for(int kk=0; kk<8; kk++){
      int f0 = kk*32 + g*8;
      bf16x8 k0 = ld_sw8(kldsb, l15, f0);
      bf16x8 k1 = ld_sw8(kldsb, 16 + l15, f0);
      st[0][0] = mfma16(k0, Qf[0][kk], st[0][0]);
      st[0][1] = mfma16(k0, Qf[1][kk], st[0][1]);
      st[1][0] = mfma16(k1, Qf[0][kk], st[1][0]);
      st[1][1] = mfma16(k1, Qf[1][kk], st[1][1]);
    }
    #pragma unroll
    for(int mi=0; mi<2; mi++)
      #pragma unroll
      for(int qn=0; qn<2; qn++)
        #pragma unroll
        for(int r=0; r<4; r++) st[mi][qn][r] *= 0.0625f;
    float tm0 = st[0][0][0], tm1 = st[0][1][0];
    #pragma unroll
    for(int mi=0; mi<2; mi++)
      #pragma unroll
      for(int r=0; r<4; r++){
        tm0 = fmaxf(tm0, st[mi][0][r]);
        tm1 = fmaxf(tm1, st[mi][1][r]);
      }
    tm0 = fmaxf(tm0, __shfl_xor(tm0, 16)); tm0 = fmaxf(tm0, __shfl_xor(tm0, 32));
    tm1 = fmaxf(tm1, __shfl_xor(tm1, 16)); tm1 = fmaxf(tm1, __shfl_xor(tm1, 32));
    float mn0 = fmaxf(mr0, tm0), mn1 = fmaxf(mr1, tm1);
    float c0 = __expf(mr0 - mn0), c1 = __expf(mr1 - mn1);
    float ts0 = 0.f, ts1 = 0.f;
    #pragma unroll
    for(int mi=0; mi<2; mi++)
      #pragma unroll
      for(int r=0; r<4; r++){
        float p0 = __expf(st[mi][0][r] - mn0); st[mi][0][r] = p0; ts0 += p0;
        float p1 = __expf(st[mi][1][r] - mn1); st[mi][1][r] = p1; ts1 += p1;
      }
    ts0 += __shfl_xor(ts0, 16); ts0 += __shfl_xor(ts0, 32);
    ts1 += __shfl_xor(ts1, 16); ts1 += __shfl_xor(ts1, 32);
    lr0 = lr0*c0 + ts0;  lr1 = lr1*c1 + ts1;  mr0 = mn0;  mr1 = mn1;
    #pragma unroll
    for(int i=0;i<16;i++){
      #pragma unroll
      for(int r=0;r<4;r++){ Ot[i][0][r] *= c0; Ot[i][1][r] *= c1; }
    }
    #pragma unroll
    for(int qn=0; qn<2; qn++)
      #pragma unroll
      for(int mi=0; mi<2; mi++)
        #pragma unroll
        for(int rp=0; rp<2; rp++){
          us16x2 pk;
          pk[0] = f2b(st[mi][qn][rp*2]);
          pk[1] = f2b(st[mi][qn][rp*2+1]);
          *(us16x2*)((char*)Psw + (qn*16 + l15)*80 + (mi*16 + g*4 + rp*2)*2) = pk;
        }
    asm volatile("" ::: "memory");
    bf16x8 pb0 = ld8(Psw + l15*40 + g*8);
    bf16x8 pb1 = ld8(Psw + (16 + l15)*40 + g*8);
    #pragma unroll
    for(int fm=0; fm<16; fm++){
      bf16x8 va = ld8(Vt + (fm*16 + l15)*40 + g*8);
      Ot[fm][0] = mfma16(va, pb0, Ot[fm][0]);
      Ot[fm][1] = mfma16(va, pb1, Ot[fm][1]);
    }
    __syncthreads();
  }

  float inv0 = 1.f/lr0, inv1 = 1.f/lr1;
  #pragma unroll
  for(int fm=0; fm<16; fm++)
    #pragma unroll
    for(int rp=0; rp<2; rp++){
      us16x2 p0, p1;
      p0[0]=f2b(Ot[fm][0][rp*2]*inv0);   p0[1]=f2b(Ot[fm][0][rp*2+1]*inv0);
      p1[0]=f2b(Ot[fm][1][rp*2]*inv1);   p1[1]=f2b(Ot[fm][1][rp*2+1]*inv1);
      *(us16x2*)((char*)Qw + l15*528      + (fm*16 + g*4 + rp*2)*2) = p0;
      *(us16x2*)((char*)Qw + (16+l15)*528 + (fm*16 + g*4 + rp*2)*2) = p1;
    }
  asm volatile("" ::: "memory");
  bf16x8 Of[2][8];
  #pragma unroll
  for(int qm=0; qm<2; qm++)
    #pragma unroll
    for(int kk=0; kk<8; kk++)
      Of[qm][kk] = ld8(Qw + (qm*16 + l15)*264 + kk*32 + g*8);
  for(int n0=0; n0<16; n0++){
    f32x4 a0 = {0,0,0,0}, a1 = {0,0,0,0};
    const us16* wrow = WoT + (size_t)(n0*16 + l15)*256;
    #pragma unroll
    for(int kk=0; kk<8; kk++){
      bf16x8 wb = ld8(wrow + kk*32 + g*8);
      a0 = mfma16(Of[0][kk], wb, a0);
      a1 = mfma16(Of[1][kk], wb, a1);
    }
    float bias = bo[n0*16 + l15];
    #pragma unroll
    for(int r=0; r<4; r++){
      yb[(size_t)(r0 + g*4 + r)*16384      + n0*128 + l15] = a0[r] + bias;
      yb[(size_t)(r0 + 16 + g*4 + r)*16384 + n0*128 + l15] = a1[r] + bias;
    }
  }
}

extern "C" void kernel_launch(void* const* d_in, const int* in_sizes, int n_in,
                              void* d_out, int out_size, void* d_ws, size_t ws_size,
                              hipStream_t stream)
{
  const float* x   = (const float*)d_in[0];
  const float* Wq  = (const float*)d_in[1];
  const float* bq  = (const float*)d_in[2];
  const float* Wk  = (const float*)d_in[3];
  const float* bk  = (const float*)d_in[4];
  const float* Wv  = (const float*)d_in[5];
  const float* bv  = (const float*)d_in[6];
  const float* Wo  = (const float*)d_in[7];
  const float* bo  = (const float*)d_in[8];
  const float* W1  = (const float*)d_in[9];
  const float* b1  = (const float*)d_in[10];
  const float* W2  = (const float*)d_in[11];
  const float* b2  = (const float*)d_in[12];
  const float* g1  = (const float*)d_in[13];
  const float* be1 = (const float*)d_in[14];
  const float* g2  = (const float*)d_in[15];
  const float* be2 = (const float*)d_in[16];
  float* out = (float*)d_out;
  char* ws = (char*)d_ws;

  const size_t KVBYTES = 134217728ull;            // 512 slots * 256 KB
  const size_t QBYTES  = 67108864ull;             // 512 slots * 128 KB
  const size_t NEED_B  = KVBYTES + 1572864ull;
  const size_t NEED_A  = KVBYTES + QBYTES + 1572864ull;

  if(ws_size >= NEED_A){
    char* Qimg  = ws + KVBYTES;
    char* wbase = ws + KVBYTES + QBYTES;
    us16* WqT = (us16*)(wbase);
    us16* WkT = (us16*)(wbase + 131072);
    us16* WvT = (us16*)(wbase + 262144);
    us16* WoT = (us16*)(wbase + 393216);
    us16* W1T = (us16*)(wbase + 524288);
    us16* W2T = (us16*)(wbase + 1048576);

    prep_w<<<dim3(256),  dim3(256), 0, stream>>>(Wq, WqT, 256, 256, 8);
    prep_w<<<dim3(256),  dim3(256), 0, stream>>>(Wk, WkT, 256, 256, 8);
    prep_w<<<dim3(256),  dim3(256), 0, stream>>>(Wv, WvT, 256, 256, 8);
    prep_w<<<dim3(256),  dim3(256), 0, stream>>>(Wo, WoT, 256, 256, 8);
    prep_w<<<dim3(1024), dim3(256), 0, stream>>>(W1, W1T, 256, 1024, 10);
    prep_w<<<dim3(1024), dim3(256), 0, stream>>>(W2, W2T, 1024, 256, 8);

    qkv_win<<<dim3(1024), dim3(256), 0, stream>>>(x, WqT, WkT, WvT, bq, bk, bv,
                                                  Qimg, ws);
    attn_hyb2<<<dim3(512), dim3(512), 0, stream>>>(Qimg, ws, WoT, bo, out);
    ffn_ln3d<<<dim3(2048), dim3(512), 0, stream>>>(out, W1T, W2T, b1, b2,
                                                   g1, be1, g2, be2);
  } else if(ws_size >= NEED_B){
    char* wbase = ws + KVBYTES;
    us16* WqT = (us16*)(wbase);
    us16* WkT = (us16*)(wbase + 131072);
    us16* WvT = (us16*)(wbase + 262144);
    us16* WoT = (us16*)(wbase + 393216);
    us16* W1T = (us16*)(wbase + 524288);
    us16* W2T = (us16*)(wbase + 1048576);

    prep_w<<<dim3(256),  dim3(256), 0, stream>>>(Wq, WqT, 256, 256, 8);
    prep_w<<<dim3(256),  dim3(256), 0, stream>>>(Wk, WkT, 256, 256, 8);
    prep_w<<<dim3(256),  dim3(256), 0, stream>>>(Wv, WvT, 256, 256, 8);
    prep_w<<<dim3(256),  dim3(256), 0, stream>>>(Wo, WoT, 256, 256, 8);
    prep_w<<<dim3(1024), dim3(256), 0, stream>>>(W1, W1T, 256, 1024, 10);
    prep_w<<<dim3(1024), dim3(256), 0, stream>>>(W2, W2T, 1024, 256, 8);

    kv_win<<<dim3(1024), dim3(256), 0, stream>>>(x, WkT, WvT, bk, bv, ws);
    attn_hyb<<<dim3(512), dim3(512), 0, stream>>>(x, WqT, bq, ws, WoT, bo, out);
    ffn_ln<<<dim3(2048), dim3(512), 0, stream>>>(out, W1T, W2T, b1, b2,
                                                 g1, be1, g2, be2);
  } else {
    us16* WqT = (us16*)(ws);
    us16* WkT = (us16*)(ws + 131072);
    us16* WvT = (us16*)(ws + 262144);
    us16* WoT = (us16*)(ws + 393216);
    us16* W1T = (us16*)(ws + 524288);
    us16* W2T = (us16*)(ws + 1048576);

    prep_w<<<dim3(256),  dim3(256), 0, stream>>>(Wq, WqT, 256, 256, 8);
    prep_w<<<dim3(256),  dim3(256), 0, stream>>>(Wk, WkT, 256, 256, 8);
    prep_w<<<dim3(256),  dim3(256), 0, stream>>>(Wv, WvT, 256, 256, 8);
    prep_w<<<dim3(256),  dim3(256), 0, stream>>>(Wo, WoT, 256, 256, 8);
    prep_w<<<dim3(1024), dim3(256), 0, stream>>>(W1, W1T, 256, 1024, 10);
    prep_w<<<dim3(1024), dim3(256), 0, stream>>>(W2, W2T, 1024, 256, 8);

    attn_win<<<dim3(512), dim3(512), 0, stream>>>(x, WqT, WkT, WvT, WoT,
                                                  bq, bk, bv, bo, out);
    ffn_ln<<<dim3(2048), dim3(512), 0, stream>>>(out, W1T, W2T, b1, b2,
                                                 g1, be1, g2, be2);
  }
}

// Round 15
// 747.989 us; speedup vs baseline: 1.0097x; 1.0097x over previous
//
#include <hip/hip_runtime.h>
#include <hip/hip_bf16.h>

// GridTransformerBlock on MI355X (gfx950).
// B=8, S=16384, E=256, FF=1024, H=W=128, G=16 -> 512 windows of 256x256.
//
// FINAL (R13-proven, 748.6 us):
// Path A (ws >= 203 MB): qkv_win -> attn_hyb2 (Q from image) -> ffn_ln3s
// Path B (ws >= 136 MB): kv_win -> attn_hyb (proven R3/R9) -> ffn_ln
// Path C: monolithic attn_win + ffn_ln (proven baseline)
//
// Ledger: __launch_bounds__ min-waves>=4 => silent corruption (R6 bisect);
// 1024-thread blocks force VGPR=64 (R7/R8); multi-block/CU residency never
// materializes at 64-132 KB LDS (R6/R11). ffn_ln's VGPR=116 Y-rematerialization
// drag fixed by LDS-staged tile (R13: 480->401us). Barrier elision via
// double-buffered h: neutral-negative (R14: 408us). Only (512,2)/(256,2) used.

typedef __bf16 bf16x8 __attribute__((ext_vector_type(8)));
typedef float  f32x4  __attribute__((ext_vector_type(4)));
typedef unsigned short us16;
typedef us16 us16x8 __attribute__((ext_vector_type(8)));
typedef us16 us16x4 __attribute__((ext_vector_type(4)));
typedef us16 us16x2 __attribute__((ext_vector_type(2)));

#define DI static __device__ __forceinline__

DI us16 f2b(float f){ __bf16 h = (__bf16)f; return __builtin_bit_cast(us16, h); }

DI bf16x8 cvt8(f32x4 a, f32x4 b){
  bf16x8 r;
  r[0]=(__bf16)a[0]; r[1]=(__bf16)a[1]; r[2]=(__bf16)a[2]; r[3]=(__bf16)a[3];
  r[4]=(__bf16)b[0]; r[5]=(__bf16)b[1]; r[6]=(__bf16)b[2]; r[7]=(__bf16)b[3];
  return r;
}
DI bf16x8 ld8(const us16* p){
  us16x8 v = *(const us16x8*)p;
  return __builtin_bit_cast(bf16x8, v);
}
DI f32x4 mfma16(bf16x8 a, bf16x8 b, f32x4 c){
  return __builtin_amdgcn_mfma_f32_16x16x32_bf16(a, b, c, 0, 0, 0);
}

// XOR-chunk-swizzled [32][256] bf16 tile, pitch 512 B (chunk = 16B of 8 bf16).
DI bf16x8 ld_sw8(const char* base, int row, int f0){ // f0 multiple of 8
  return ld8((const us16*)(base + row*512 + ((((f0>>3) ^ (row&7))) << 4)));
}
DI void st_sw1(char* base, int row, int f, us16 v){
  *(us16*)(base + row*512 + ((((f>>3) ^ (row&7))) << 4) + (f&7)*2) = v;
}
DI void st_sw4(char* base, int row, int f0, us16x4 v){ // f0 multiple of 4
  *(us16x4*)(base + row*512 + ((((f0>>3) ^ (row&7))) << 4) + (f0&7)*2) = v;
}

// V^T tile [256 f][32 k] bf16, pitch 64 B, chunk-swizzle c ^= (row>>1)&3 (2-way max).
DI bf16x8 ld_vt(const char* base, int row, int gg){
  return ld8((const us16*)(base + row*64 + (((gg ^ ((row>>1)&3))) << 4)));
}
DI void st_vt(char* base, int row, int col, us16 v){
  int c = col >> 3;
  *(us16*)(base + row*64 + (((c ^ ((row>>1)&3))) << 4) + (col&7)*2) = v;
}

// ---------------- weight prep: bf16 + transpose to [out][in] rows -----------
__global__ void prep_w(const float* __restrict__ src, us16* __restrict__ dst,
                       int R, int C, int cshift){
  int idx = blockIdx.x*256 + threadIdx.x;
  if(idx >= R*C) return;
  int r = idx >> cshift;          // row in src (R x C)
  int c = idx & (C-1);
  dst[(size_t)c*R + r] = f2b(src[idx]);   // dst is C x R
}

// =====================================================================
// K1a: Q/K/V projection (Path A). [PROVEN R10/R12/R13]
// =====================================================================
__global__ __launch_bounds__(256, 2)
void qkv_win(const float* __restrict__ x,
             const us16* __restrict__ WqT, const us16* __restrict__ WkT,
             const us16* __restrict__ WvT,
             const float* __restrict__ bq, const float* __restrict__ bk,
             const float* __restrict__ bv,
             char* __restrict__ Qimg, char* __restrict__ KV)
{
  __shared__ __align__(16) char smem[65536];
  const int tid = threadIdx.x;
  const int wl = tid >> 6, lane = tid & 63, l15 = lane & 15, g = lane >> 4;
  const int blk = blockIdx.x;
  const int hw = blk & 1, tg = (blk>>1)&7, wh = (blk>>4)&7, b = blk>>7;
  const int win = wh*8 + hw*4 + wl;

  {
    const float* xb = x + (size_t)b*4194304 + (size_t)(tg*32)*16384 + wh*2048 + hw*64;
    const int prow = tid >> 4, pc = tid & 15;
    char* abase = smem + (pc>>2)*16384;
    const int f0 = prow*16 + (pc&3)*4;
    for(int t=0; t<32; t++){
      f32x4 v = *(const f32x4*)(xb + (size_t)t*16384 + prow*128 + pc*4);
      us16x4 pk; pk[0]=f2b(v[0]); pk[1]=f2b(v[1]); pk[2]=f2b(v[2]); pk[3]=f2b(v[3]);
      st_sw4(abase, t, f0, pk);
    }
  }
  __syncthreads();
  bf16x8 tA[2][8];
  #pragma unroll
  for(int mi=0; mi<2; mi++)
    #pragma unroll
    for(int kk=0; kk<8; kk++)
      tA[mi][kk] = ld_sw8(smem + wl*16384, mi*16 + l15, kk*32 + g*8);
  __syncthreads();

  char* outb = smem + wl*16384;
  const size_t wslot = (size_t)(b*64 + win);

  // ---- Q ----
  for(int n0=0; n0<16; n0++){
    f32x4 a0 = {0,0,0,0}, a1 = {0,0,0,0};
    const us16* wrow = WqT + (size_t)(n0*16 + l15)*256;
    #pragma unroll
    for(int kk=0; kk<8; kk++){
      bf16x8 wb = ld8(wrow + kk*32 + g*8);
      a0 = mfma16(tA[0][kk], wb, a0);
      a1 = mfma16(tA[1][kk], wb, a1);
    }
    float bias = bq[n0*16 + l15];
    #pragma unroll
    for(int r=0; r<4; r++){
      st_sw1(outb, g*4+r,    n0*16+l15, f2b(a0[r] + bias));
      st_sw1(outb, 16+g*4+r, n0*16+l15, f2b(a1[r] + bias));
    }
  }
  asm volatile("" ::: "memory");
  {
    char* dst = Qimg + (wslot*8 + tg)*16384;
    #pragma unroll
    for(int i=0; i<16; i++)
      *(us16x8*)(dst + i*1024 + lane*16) = *(const us16x8*)(outb + i*1024 + lane*16);
  }
  asm volatile("" ::: "memory");

  // ---- K ----
  for(int n0=0; n0<16; n0++){
    f32x4 a0 = {0,0,0,0}, a1 = {0,0,0,0};
    const us16* wrow = WkT + (size_t)(n0*16 + l15)*256;
    #pragma unroll
    for(int kk=0; kk<8; kk++){
      bf16x8 wb = ld8(wrow + kk*32 + g*8);
      a0 = mfma16(tA[0][kk], wb, a0);
      a1 = mfma16(tA[1][kk], wb, a1);
    }
    float bias = bk[n0*16 + l15];
    #pragma unroll
    for(int r=0; r<4; r++){
      st_sw1(outb, g*4+r,    n0*16+l15, f2b(a0[r] + bias));
      st_sw1(outb, 16+g*4+r, n0*16+l15, f2b(a1[r] + bias));
    }
  }
  asm volatile("" ::: "memory");
  {
    char* dst = KV + wslot*262144 + tg*16384;
    #pragma unroll
    for(int i=0; i<16; i++)
      *(us16x8*)(dst + i*1024 + lane*16) = *(const us16x8*)(outb + i*1024 + lane*16);
  }
  asm volatile("" ::: "memory");

  // ---- V^T ----
  for(int n0=0; n0<16; n0++){
    f32x4 a0 = {0,0,0,0}, a1 = {0,0,0,0};
    const us16* wrow = WvT + (size_t)(n0*16 + l15)*256;
    f32x4 bv4 = *(const f32x4*)(bv + n0*16 + g*4);
    #pragma unroll
    for(int kk=0; kk<8; kk++){
      bf16x8 wa = ld8(wrow + kk*32 + g*8);
      a0 = mfma16(wa, tA[0][kk], a0);
      a1 = mfma16(wa, tA[1][kk], a1);
    }
    #pragma unroll
    for(int r=0; r<4; r++){
      int jr = n0*16 + g*4 + r;
      st_vt(outb, jr, l15,      f2b(a0[r] + bv4[r]));
      st_vt(outb, jr, 16 + l15, f2b(a1[r] + bv4[r]));
    }
  }
  asm volatile("" ::: "memory");
  {
    char* dst = KV + wslot*262144 + 131072 + tg*16384;
    #pragma unroll
    for(int i=0; i<16; i++)
      *(us16x8*)(dst + i*1024 + lane*16) = *(const us16x8*)(outb + i*1024 + lane*16);
  }
}

// =====================================================================
// K1b: K/V-only projection (Path B, PROVEN R3/R9 verbatim)
// =====================================================================
__global__ __launch_bounds__(256, 2)
void kv_win(const float* __restrict__ x,
            const us16* __restrict__ WkT, const us16* __restrict__ WvT,
            const float* __restrict__ bk, const float* __restrict__ bv,
            char* __restrict__ KV)
{
  __shared__ __align__(16) char smem[65536];
  const int tid = threadIdx.x;
  const int wl = tid >> 6, lane = tid & 63, l15 = lane & 15, g = lane >> 4;
  const int blk = blockIdx.x;
  const int hw = blk & 1, tg = (blk>>1)&7, wh = (blk>>4)&7, b = blk>>7;
  const int win = wh*8 + hw*4 + wl;

  {
    const float* xb = x + (size_t)b*4194304 + (size_t)(tg*32)*16384 + wh*2048 + hw*64;
    const int prow = tid >> 4, pc = tid & 15;
    char* abase = smem + (pc>>2)*16384;
    const int f0 = prow*16 + (pc&3)*4;
    for(int t=0; t<32; t++){
      f32x4 v = *(const f32x4*)(xb + (size_t)t*16384 + prow*128 + pc*4);
      us16x4 pk; pk[0]=f2b(v[0]); pk[1]=f2b(v[1]); pk[2]=f2b(v[2]); pk[3]=f2b(v[3]);
      st_sw4(abase, t, f0, pk);
    }
  }
  __syncthreads();
  bf16x8 tA[2][8];
  #pragma unroll
  for(int mi=0; mi<2; mi++)
    #pragma unroll
    for(int kk=0; kk<8; kk++)
      tA[mi][kk] = ld_sw8(smem + wl*16384, mi*16 + l15, kk*32 + g*8);
  __syncthreads();

  char* outb = smem + wl*16384;
  const size_t wslot = (size_t)(b*64 + win);

  for(int n0=0; n0<16; n0++){
    f32x4 a0 = {0,0,0,0}, a1 = {0,0,0,0};
    const us16* wrow = WkT + (size_t)(n0*16 + l15)*256;
    #pragma unroll
    for(int kk=0; kk<8; kk++){
      bf16x8 wb = ld8(wrow + kk*32 + g*8);
      a0 = mfma16(tA[0][kk], wb, a0);
      a1 = mfma16(tA[1][kk], wb, a1);
    }
    float bias = bk[n0*16 + l15];
    #pragma unroll
    for(int r=0; r<4; r++){
      st_sw1(outb, g*4+r,    n0*16+l15, f2b(a0[r] + bias));
      st_sw1(outb, 16+g*4+r, n0*16+l15, f2b(a1[r] + bias));
    }
  }
  asm volatile("" ::: "memory");
  {
    char* dst = KV + wslot*262144 + tg*16384;
    #pragma unroll
    for(int i=0; i<16; i++)
      *(us16x8*)(dst + i*1024 + lane*16) = *(const us16x8*)(outb + i*1024 + lane*16);
  }
  asm volatile("" ::: "memory");

  for(int n0=0; n0<16; n0++){
    f32x4 a0 = {0,0,0,0}, a1 = {0,0,0,0};
    const us16* wrow = WvT + (size_t)(n0*16 + l15)*256;
    f32x4 bv4 = *(const f32x4*)(bv + n0*16 + g*4);
    #pragma unroll
    for(int kk=0; kk<8; kk++){
      bf16x8 wa = ld8(wrow + kk*32 + g*8);
      a0 = mfma16(wa, tA[0][kk], a0);
      a1 = mfma16(wa, tA[1][kk], a1);
    }
    #pragma unroll
    for(int r=0; r<4; r++){
      int jr = n0*16 + g*4 + r;
      st_vt(outb, jr, l15,      f2b(a0[r] + bv4[r]));
      st_vt(outb, jr, 16 + l15, f2b(a1[r] + bv4[r]));
    }
  }
  asm volatile("" ::: "memory");
  {
    char* dst = KV + wslot*262144 + 131072 + tg*16384;
    #pragma unroll
    for(int i=0; i<16; i++)
      *(us16x8*)(dst + i*1024 + lane*16) = *(const us16x8*)(outb + i*1024 + lane*16);
  }
}

// =====================================================================
// K2 shared helpers + core loop [PROVEN R10/R12/R13]
// =====================================================================
DI void load_kv_regs(const char* slot, int kt, us16x8* r, int wid, int lane){
  const char* src = (wid < 4)
      ? slot + (size_t)kt*16384 + wid*4096
      : slot + 131072 + (size_t)kt*16384 + (wid-4)*4096;
  #pragma unroll
  for(int i=0; i<4; i++)
    r[i] = *(const us16x8*)(src + i*1024 + lane*16);
}
DI void write_kv_lds(char* kb, char* vb, const us16x8* r, int wid, int lane){
  char* dst = (wid < 4) ? kb + wid*4096 : vb + (wid-4)*4096;
  #pragma unroll
  for(int i=0; i<4; i++)
    *(us16x8*)(dst + i*1024 + lane*16) = r[i];
}

DI void attn_core_loop(char* smem, us16* Psw, const char* slot,
                       const bf16x8 Qf[2][8], us16x8* stg,
                       const us16* WoT, const float* bo, float* yb,
                       int wid, int lane, int l15, int g, int r0)
{
  us16* Qw = (us16*)(smem) + wid*(32*264);
  float mr0 = -1e30f, mr1 = -1e30f, lr0 = 0.f, lr1 = 0.f;
  f32x4 Ot[16][2];
  const f32x4 zf = {0,0,0,0};
  #pragma unroll
  for(int i=0;i<16;i++){ Ot[i][0]=zf; Ot[i][1]=zf; }
  __syncthreads();               // tile 0 staged

  for(int kt=0; kt<8; kt++){
    char* kb = (kt&1) ? smem + 16384 : smem;
    char* vb = (kt&1) ? smem + 49152 : smem + 32768;
    if(kt < 7) load_kv_regs(slot, kt+1, stg, wid, lane);
    f32x4 st[2][2] = {{zf,zf},{zf,zf}};
    #pragma unroll
    for(int kk=0; kk<8; kk++){
      int f0 = kk*32 + g*8;
      bf16x8 k0 = ld_sw8(kb, l15, f0);
      bf16x8 k1 = ld_sw8(kb, 16 + l15, f0);
      st[0][0] = mfma16(k0, Qf[0][kk], st[0][0]);
      st[0][1] = mfma16(k0, Qf[1][kk], st[0][1]);
      st[1][0] = mfma16(k1, Qf[0][kk], st[1][0]);
      st[1][1] = mfma16(k1, Qf[1][kk], st[1][1]);
    }
    #pragma unroll
    for(int mi=0; mi<2; mi++)
      #pragma unroll
      for(int qn=0; qn<2; qn++)
        #pragma unroll
        for(int r=0; r<4; r++) st[mi][qn][r] *= 0.0625f;
    float tm0 = st[0][0][0], tm1 = st[0][1][0];
    #pragma unroll
    for(int mi=0; mi<2; mi++)
      #pragma unroll
      for(int r=0; r<4; r++){
        tm0 = fmaxf(tm0, st[mi][0][r]);
        tm1 = fmaxf(tm1, st[mi][1][r]);
      }
    tm0 = fmaxf(tm0, __shfl_xor(tm0, 16)); tm0 = fmaxf(tm0, __shfl_xor(tm0, 32));
    tm1 = fmaxf(tm1, __shfl_xor(tm1, 16)); tm1 = fmaxf(tm1, __shfl_xor(tm1, 32));
    float mn0 = fmaxf(mr0, tm0), mn1 = fmaxf(mr1, tm1);
    float c0 = __expf(mr0 - mn0), c1 = __expf(mr1 - mn1);
    float ts0 = 0.f, ts1 = 0.f;
    #pragma unroll
    for(int mi=0; mi<2; mi++)
      #pragma unroll
      for(int r=0; r<4; r++){
        float p0 = __expf(st[mi][0][r] - mn0); st[mi][0][r] = p0; ts0 += p0;
        float p1 = __expf(st[mi][1][r] - mn1); st[mi][1][r] = p1; ts1 += p1;
      }
    ts0 += __shfl_xor(ts0, 16); ts0 += __shfl_xor(ts0, 32);
    ts1 += __shfl_xor(ts1, 16); ts1 += __shfl_xor(ts1, 32);
    lr0 = lr0*c0 + ts0;  lr1 = lr1*c1 + ts1;  mr0 = mn0;  mr1 = mn1;
    #pragma unroll
    for(int i=0;i<16;i++){
      #pragma unroll
      for(int r=0;r<4;r++){ Ot[i][0][r] *= c0; Ot[i][1][r] *= c1; }
    }
    #pragma unroll
    for(int qn=0; qn<2; qn++)
      #pragma unroll
      for(int mi=0; mi<2; mi++)
        #pragma unroll
        for(int rp=0; rp<2; rp++){
          us16x2 pk;
          pk[0] = f2b(st[mi][qn][rp*2]);
          pk[1] = f2b(st[mi][qn][rp*2+1]);
          *(us16x2*)((char*)Psw + (qn*16 + l15)*80 + (mi*16 + g*4 + rp*2)*2) = pk;
        }
    asm volatile("" ::: "memory");
    bf16x8 pb0 = ld8(Psw + l15*40 + g*8);
    bf16x8 pb1 = ld8(Psw + (16 + l15)*40 + g*8);
    #pragma unroll
    for(int fm=0; fm<16; fm++){
      bf16x8 va = ld_vt(vb, fm*16 + l15, g);
      Ot[fm][0] = mfma16(va, pb0, Ot[fm][0]);
      Ot[fm][1] = mfma16(va, pb1, Ot[fm][1]);
    }
    if(kt < 7){
      char* kbn = (kt&1) ? smem : smem + 16384;
      char* vbn = (kt&1) ? smem + 32768 : smem + 49152;
      write_kv_lds(kbn, vbn, stg, wid, lane);
    }
    __syncthreads();
  }

  float inv0 = 1.f/lr0, inv1 = 1.f/lr1;
  #pragma unroll
  for(int fm=0; fm<16; fm++)
    #pragma unroll
    for(int rp=0; rp<2; rp++){
      us16x2 p0, p1;
      p0[0]=f2b(Ot[fm][0][rp*2]*inv0);   p0[1]=f2b(Ot[fm][0][rp*2+1]*inv0);
      p1[0]=f2b(Ot[fm][1][rp*2]*inv1);   p1[1]=f2b(Ot[fm][1][rp*2+1]*inv1);
      *(us16x2*)((char*)Qw + l15*528      + (fm*16 + g*4 + rp*2)*2) = p0;
      *(us16x2*)((char*)Qw + (16+l15)*528 + (fm*16 + g*4 + rp*2)*2) = p1;
    }
  asm volatile("" ::: "memory");
  bf16x8 Of[2][8];
  #pragma unroll
  for(int qm=0; qm<2; qm++)
    #pragma unroll
    for(int kk=0; kk<8; kk++)
      Of[qm][kk] = ld8(Qw + (qm*16 + l15)*264 + kk*32 + g*8);
  for(int n0=0; n0<16; n0++){
    f32x4 a0 = {0,0,0,0}, a1 = {0,0,0,0};
    const us16* wrow = WoT + (size_t)(n0*16 + l15)*256;
    #pragma unroll
    for(int kk=0; kk<8; kk++){
      bf16x8 wb = ld8(wrow + kk*32 + g*8);
      a0 = mfma16(Of[0][kk], wb, a0);
      a1 = mfma16(Of[1][kk], wb, a1);
    }
    float bias = bo[n0*16 + l15];
    #pragma unroll
    for(int r=0; r<4; r++){
      yb[(size_t)(r0 + g*4 + r)*16384      + n0*128 + l15] = a0[r] + bias;
      yb[(size_t)(r0 + 16 + g*4 + r)*16384 + n0*128 + l15] = a1[r] + bias;
    }
  }
}

// ---- Path A: Q from image [PROVEN R10/R12/R13] ----
__global__ __launch_bounds__(512, 2)
void attn_hyb2(const char* __restrict__ Qimg, const char* __restrict__ KV,
               const us16* __restrict__ WoT, const float* __restrict__ bo,
               float* __restrict__ y)
{
  __shared__ __align__(16) char smem[135168];
  const int tid = threadIdx.x, wid = tid>>6, lane = tid&63, l15 = lane&15, g = lane>>4;
  const int blk = blockIdx.x;
  const int b   = blk >> 6;
  const int win = blk & 63;
  const size_t base = (size_t)b*4194304 + (size_t)(win>>3)*2048 + (size_t)(win&7)*16;
  float*       yb = y + base;
  const char*  slot = KV + (size_t)blk*262144;
  const char*  Qt = Qimg + ((size_t)blk*8 + wid)*16384;
  us16* Psw = (us16*)(smem + 65536) + wid*1280;
  const int r0 = wid*32;

  us16x8 stg[4];
  load_kv_regs(slot, 0, stg, wid, lane);

  bf16x8 Qf[2][8];
  #pragma unroll
  for(int qn=0; qn<2; qn++)
    #pragma unroll
    for(int kk=0; kk<8; kk++){
      int row = qn*16 + l15;
      Qf[qn][kk] = ld8((const us16*)(Qt + row*512 + ((((kk*4+g) ^ (l15&7))) << 4)));
    }

  write_kv_lds(smem, smem + 32768, stg, wid, lane);
  attn_core_loop(smem, Psw, slot, Qf, stg, WoT, bo, yb, wid, lane, l15, g, r0);
}

// ---- Path B: proven phase-A Q ----
__global__ __launch_bounds__(512, 2)
void attn_hyb(const float* __restrict__ x,
              const us16* __restrict__ WqT, const float* __restrict__ bq,
              const char* __restrict__ KV,
              const us16* __restrict__ WoT, const float* __restrict__ bo,
              float* __restrict__ y)
{
  __shared__ __align__(16) char smem[135168];
  const int tid = threadIdx.x, wid = tid>>6, lane = tid&63, l15 = lane&15, g = lane>>4;
  const int blk = blockIdx.x;
  const int b   = blk >> 6;
  const int win = blk & 63;
  const size_t base = (size_t)b*4194304 + (size_t)(win>>3)*2048 + (size_t)(win&7)*16;
  const float* xb = x + base;
  float*       yb = y + base;
  const char*  slot = KV + (size_t)blk*262144;

  us16* Qw  = (us16*)(smem) + wid*(32*264);
  us16* Psw = (us16*)(smem + 65536) + wid*1280;
  const int r0 = wid*32;

  us16x8 stg[4];
  load_kv_regs(slot, 0, stg, wid, lane);

  bf16x8 tA[2][8];
  #pragma unroll
  for(int mi=0; mi<2; mi++){
    const float* trow = xb + (size_t)(r0 + mi*16 + l15)*16384;
    #pragma unroll
    for(int kk=0; kk<8; kk++){
      int f0 = kk*32 + g*8;
      const float* p = trow + (f0>>4)*128 + (f0&15);
      tA[mi][kk] = cvt8(*(const f32x4*)p, *(const f32x4*)(p+4));
    }
  }
  for(int n0=0; n0<16; n0++){
    f32x4 a0 = {0,0,0,0}, a1 = {0,0,0,0};
    const us16* wrow = WqT + (size_t)(n0*16 + l15)*256;
    #pragma unroll
    for(int kk=0; kk<8; kk++){
      bf16x8 wb = ld8(wrow + kk*32 + g*8);
      a0 = mfma16(tA[0][kk], wb, a0);
      a1 = mfma16(tA[1][kk], wb, a1);
    }
    float bias = bq[n0*16 + l15];
    #pragma unroll
    for(int r=0; r<4; r++){
      Qw[(g*4+r)*264      + n0*16 + l15] = f2b(a0[r] + bias);
      Qw[(16+g*4+r)*264   + n0*16 + l15] = f2b(a1[r] + bias);
    }
  }
  asm volatile("" ::: "memory");
  bf16x8 Qf[2][8];
  #pragma unroll
  for(int qn=0; qn<2; qn++)
    #pragma unroll
    for(int kk=0; kk<8; kk++)
      Qf[qn][kk] = ld8(Qw + (qn*16 + l15)*264 + kk*32 + g*8);
  __syncthreads();

  write_kv_lds(smem, smem + 32768, stg, wid, lane);
  attn_core_loop(smem, Psw, slot, Qf, stg, WoT, bo, yb, wid, lane, l15, g, r0);
}

// =====================================================================
// K3a: FFN sliced, LDS-staged Y tile, (512,2). FF in 4 slices of 256.
// Bit-identical accumulation order vs ffn_ln (q*256+32*kk enumerates the
// monolithic kk order); same f2b rounding points. LDS 67584 B. [PROVEN R13]
// =====================================================================
__global__ __launch_bounds__(512, 2)
void ffn_ln3s(float* y,   // d_out, in-place
              const us16* __restrict__ W1T, const us16* __restrict__ W2T,
              const float* __restrict__ b1, const float* __restrict__ b2,
              const float* __restrict__ g1, const float* __restrict__ be1,
              const float* __restrict__ g2, const float* __restrict__ be2)
{
  __shared__ __align__(16) char smem[67584];
  us16* tile = (us16*)smem;              // [64][264] bf16 y rows
  us16* h    = (us16*)(smem + 33792);    // [64][264] bf16 FF-slice
  float* fl  = (float*)smem;             // overlay after GEMMs: [64][260] f32
  const int tid = threadIdx.x, wid = tid>>6, lane = tid&63, l15 = lane&15, g = lane>>4;
  float* Y = y + (size_t)blockIdx.x*64*256;

  { // stage: 64 canonical rows (1 KB contiguous each) -> bf16 tile (read ONCE)
    #pragma unroll
    for(int rr=0; rr<8; rr++){
      int row = wid*8 + rr;
      f32x4 v = *(const f32x4*)(Y + (size_t)row*256 + lane*4);
      us16x4 pk; pk[0]=f2b(v[0]); pk[1]=f2b(v[1]); pk[2]=f2b(v[2]); pk[3]=f2b(v[3]);
      *(us16x4*)(tile + row*264 + lane*4) = pk;
    }
  }
  __syncthreads();

  const f32x4 zf = {0,0,0,0};
  f32x4 acc2[4][2] = {{zf,zf},{zf,zf},{zf,zf},{zf,zf}};
  for(int q=0; q<4; q++){
    // phase 1: h = gelu(tile @ W1[:, q*256 .. +255] + b1)
    f32x4 acc[4][2] = {{zf,zf},{zf,zf},{zf,zf},{zf,zf}};
    #pragma unroll
    for(int kk=0; kk<8; kk++){
      int f0 = kk*32 + g*8;
      bf16x8 ya[4];
      #pragma unroll
      for(int mi=0; mi<4; mi++) ya[mi] = ld8(tile + (mi*16 + l15)*264 + f0);
      #pragma unroll
      for(int n=0; n<2; n++){
        bf16x8 wb = ld8(W1T + (size_t)(q*256 + wid*32 + n*16 + l15)*256 + f0);
        #pragma unroll
        for(int mi=0; mi<4; mi++) acc[mi][n] = mfma16(ya[mi], wb, acc[mi][n]);
      }
    }
    #pragma unroll
    for(int n=0; n<2; n++){
      int jl = wid*32 + n*16 + l15;
      float bias = b1[q*256 + jl];
      #pragma unroll
      for(int mi=0; mi<4; mi++)
        #pragma unroll
        for(int r=0; r<4; r++){
          float v = acc[mi][n][r] + bias;
          v = 0.5f*v*(1.f + erff(v*0.70710678118654752f));   // exact GELU
          h[(mi*16 + g*4 + r)*264 + jl] = f2b(v);
        }
    }
    __syncthreads();
    // phase 2: acc2 += h @ W2[q*256.., :]   (same K-chunk order as monolithic)
    #pragma unroll
    for(int kk=0; kk<8; kk++){
      int f0 = kk*32 + g*8;
      bf16x8 ha[4];
      #pragma unroll
      for(int mi=0; mi<4; mi++) ha[mi] = ld8(h + (mi*16 + l15)*264 + f0);
      #pragma unroll
      for(int n=0; n<2; n++){
        bf16x8 wb = ld8(W2T + (size_t)(wid*32 + n*16 + l15)*1024 + q*256 + f0);
        #pragma unroll
        for(int mi=0; mi<4; mi++) acc2[mi][n] = mfma16(ha[mi], wb, acc2[mi][n]);
      }
    }
    __syncthreads();   // h reads done before next slice's phase-1 overwrites
  }
  // ffn result (f32) -> fl overlay
  #pragma unroll
  for(int n=0; n<2; n++){
    float bias = b2[wid*32 + n*16 + l15];
    #pragma unroll
    for(int mi=0; mi<4; mi++)
      #pragma unroll
      for(int r=0; r<4; r++)
        fl[(mi*16 + g*4 + r)*260 + wid*32 + n*16 + l15] = acc2[mi][n][r] + bias;
  }
  __syncthreads();
  // phase 3: per-row LN(ffn) + residual, then LN again + residual
  f32x4 G1  = *(const f32x4*)(g1  + lane*4);
  f32x4 BE1 = *(const f32x4*)(be1 + lane*4);
  f32x4 G2  = *(const f32x4*)(g2  + lane*4);
  f32x4 BE2 = *(const f32x4*)(be2 + lane*4);
  for(int rr=0; rr<8; rr++){
    int row = wid*8 + rr;
    f32x4 f  = *(const f32x4*)(fl + row*260 + lane*4);
    f32x4 yv = *(const f32x4*)(Y + (size_t)row*256 + lane*4);
    float s  = f[0]+f[1]+f[2]+f[3];
    float s2 = f[0]*f[0]+f[1]*f[1]+f[2]*f[2]+f[3]*f[3];
    #pragma unroll
    for(int m=1; m<=32; m<<=1){ s += __shfl_xor(s, m); s2 += __shfl_xor(s2, m); }
    float mu = s*(1.f/256.f);
    float rs = rsqrtf(fmaxf(s2*(1.f/256.f) - mu*mu, 0.f) + 1e-5f);
    f32x4 y1;
    #pragma unroll
    for(int i=0; i<4; i++) y1[i] = yv[i] + (f[i]-mu)*rs*G1[i] + BE1[i];
    float t1 = y1[0]+y1[1]+y1[2]+y1[3];
    float t2 = y1[0]*y1[0]+y1[1]*y1[1]+y1[2]*y1[2]+y1[3]*y1[3];
    #pragma unroll
    for(int m=1; m<=32; m<<=1){ t1 += __shfl_xor(t1, m); t2 += __shfl_xor(t2, m); }
    float mu2 = t1*(1.f/256.f);
    float rs2 = rsqrtf(fmaxf(t2*(1.f/256.f) - mu2*mu2, 0.f) + 1e-5f);
    f32x4 o;
    #pragma unroll
    for(int i=0; i<4; i++) o[i] = y1[i] + (y1[i]-mu2)*rs2*G2[i] + BE2[i];
    *(f32x4*)(Y + (size_t)row*256 + lane*4) = o;
  }
}

// =====================================================================
// K3b: FFN + 2x LN + residuals (PROVEN 64-row template, Paths B/C)
// =====================================================================
__global__ __launch_bounds__(512, 2)
void ffn_ln(float* y,   // d_out, in-place
            const us16* __restrict__ W1T, const us16* __restrict__ W2T,
            const float* __restrict__ b1, const float* __restrict__ b2,
            const float* __restrict__ g1, const float* __restrict__ be1,
            const float* __restrict__ g2, const float* __restrict__ be2)
{
  __shared__ __align__(16) char smem[132096];
  us16*  h  = (us16*)smem;    // [64][1032] bf16, pitch 2064 B
  float* fl = (float*)smem;   // overlay: [64][260] f32, pitch 1040 B
  const int tid = threadIdx.x, wid = tid>>6, lane = tid&63, l15 = lane&15, g = lane>>4;
  float* Y = y + (size_t)blockIdx.x*64*256;

  bf16x8 ya[4][8];
  #pragma unroll
  for(int mi=0; mi<4; mi++){
    const float* p = Y + (size_t)(mi*16 + l15)*256;
    #pragma unroll
    for(int kk=0; kk<8; kk++){
      int f0 = kk*32 + g*8;
      ya[mi][kk] = cvt8(*(const f32x4*)(p + f0), *(const f32x4*)(p + f0 + 4));
    }
  }
  const f32x4 zf = {0,0,0,0};
  #pragma unroll 2
  for(int n0=0; n0<8; n0++){
    int j = wid*128 + n0*16 + l15;
    f32x4 acc[4] = {zf,zf,zf,zf};
    const us16* wrow = W1T + (size_t)j*256;
    #pragma unroll
    for(int kk=0; kk<8; kk++){
      bf16x8 wb = ld8(wrow + kk*32 + g*8);
      #pragma unroll
      for(int mi=0; mi<4; mi++) acc[mi] = mfma16(ya[mi][kk], wb, acc[mi]);
    }
    float bias = b1[j];
    #pragma unroll
    for(int mi=0; mi<4; mi++)
      #pragma unroll
      for(int r=0; r<4; r++){
        float v = acc[mi][r] + bias;
        v = 0.5f*v*(1.f + erff(v*0.70710678118654752f));   // exact GELU
        h[(mi*16 + g*4 + r)*1032 + j] = f2b(v);
      }
  }
  __syncthreads();
  f32x4 acc2[4][2] = {{zf,zf},{zf,zf},{zf,zf},{zf,zf}};
  #pragma unroll 2
  for(int kk=0; kk<32; kk++){
    int f0 = kk*32 + g*8;
    bf16x8 ha[4];
    #pragma unroll
    for(int mi=0; mi<4; mi++) ha[mi] = ld8(h + (mi*16 + l15)*1032 + f0);
    #pragma unroll
    for(int n=0; n<2; n++){
      bf16x8 wb = ld8(W2T + (size_t)(wid*32 + n*16 + l15)*1024 + f0);
      #pragma unroll
      for(int mi=0; mi<4; mi++) acc2[mi][n] = mfma16(ha[mi], wb, acc2[mi][n]);
    }
  }
  __syncthreads();
  #pragma unroll
  for(int mi=0; mi<4; mi++)
    #pragma unroll
    for(int n=0; n<2; n++){
      float bias = b2[wid*32 + n*16 + l15];
      #pragma unroll
      for(int r=0; r<4; r++)
        fl[(mi*16 + g*4 + r)*260 + wid*32 + n*16 + l15] = acc2[mi][n][r] + bias;
    }
  __syncthreads();
  f32x4 G1  = *(const f32x4*)(g1  + lane*4);
  f32x4 BE1 = *(const f32x4*)(be1 + lane*4);
  f32x4 G2  = *(const f32x4*)(g2  + lane*4);
  f32x4 BE2 = *(const f32x4*)(be2 + lane*4);
  for(int rr=0; rr<8; rr++){
    int row = wid*8 + rr;
    f32x4 f  = *(const f32x4*)(fl + row*260 + lane*4);
    f32x4 yv = *(const f32x4*)(Y + (size_t)row*256 + lane*4);
    float s  = f[0]+f[1]+f[2]+f[3];
    float s2 = f[0]*f[0]+f[1]*f[1]+f[2]*f[2]+f[3]*f[3];
    #pragma unroll
    for(int m=1; m<=32; m<<=1){ s += __shfl_xor(s, m); s2 += __shfl_xor(s2, m); }
    float mu = s*(1.f/256.f);
    float rs = rsqrtf(fmaxf(s2*(1.f/256.f) - mu*mu, 0.f) + 1e-5f);
    f32x4 y1;
    #pragma unroll
    for(int i=0; i<4; i++) y1[i] = yv[i] + (f[i]-mu)*rs*G1[i] + BE1[i];
    float t1 = y1[0]+y1[1]+y1[2]+y1[3];
    float t2 = y1[0]*y1[0]+y1[1]*y1[1]+y1[2]*y1[2]+y1[3]*y1[3];
    #pragma unroll
    for(int m=1; m<=32; m<<=1){ t1 += __shfl_xor(t1, m); t2 += __shfl_xor(t2, m); }
    float mu2 = t1*(1.f/256.f);
    float rs2 = rsqrtf(fmaxf(t2*(1.f/256.f) - mu2*mu2, 0.f) + 1e-5f);
    f32x4 o;
    #pragma unroll
    for(int i=0; i<4; i++) o[i] = y1[i] + (y1[i]-mu2)*rs2*G2[i] + BE2[i];
    *(f32x4*)(Y + (size_t)row*256 + lane*4) = o;
  }
}

// =====================================================================
// FALLBACK: fully proven monolithic attention (used if ws too small)
// =====================================================================
__global__ __launch_bounds__(512, 2)
void attn_win(const float* __restrict__ x,
              const us16* __restrict__ WqT, const us16* __restrict__ WkT,
              const us16* __restrict__ WvT, const us16* __restrict__ WoT,
              const float* __restrict__ bq, const float* __restrict__ bk,
              const float* __restrict__ bv, const float* __restrict__ bo,
              float* __restrict__ y)
{
  __shared__ __align__(16) char smem[135168];
  const int tid = threadIdx.x;
  const int wid = tid >> 6;
  const int lane = tid & 63;
  const int l15 = lane & 15;
  const int g = lane >> 4;

  const int blk = blockIdx.x;
  const int b   = blk >> 6;
  const int win = blk & 63;
  const size_t base = (size_t)b*4194304 + (size_t)(win>>3)*2048 + (size_t)(win&7)*16;
  const float* xb = x + base;
  float*       yb = y + base;

  us16* Qw    = (us16*)(smem) + wid*(32*264);
  char* slabb = smem;
  char* kldsb = smem + 16384;
  us16* Vt    = (us16*)(smem + 32768);
  us16* Psw   = (us16*)(smem + 53248) + wid*1280;

  const int r0 = wid*32;

  bf16x8 tA[2][8];
  #pragma unroll
  for(int mi=0; mi<2; mi++){
    const float* trow = xb + (size_t)(r0 + mi*16 + l15)*16384;
    #pragma unroll
    for(int kk=0; kk<8; kk++){
      int f0 = kk*32 + g*8;
      const float* p = trow + (f0>>4)*128 + (f0&15);
      tA[mi][kk] = cvt8(*(const f32x4*)p, *(const f32x4*)(p+4));
    }
  }
  for(int n0=0; n0<16; n0++){
    f32x4 a0 = {0,0,0,0}, a1 = {0,0,0,0};
    const us16* wrow = WqT + (size_t)(n0*16 + l15)*256;
    #pragma unroll
    for(int kk=0; kk<8; kk++){
      bf16x8 wb = ld8(wrow + kk*32 + g*8);
      a0 = mfma16(tA[0][kk], wb, a0);
      a1 = mfma16(tA[1][kk], wb, a1);
    }
    float bias = bq[n0*16 + l15];
    #pragma unroll
    for(int r=0; r<4; r++){
      Qw[(g*4+r)*264      + n0*16 + l15] = f2b(a0[r] + bias);
      Qw[(16+g*4+r)*264   + n0*16 + l15] = f2b(a1[r] + bias);
    }
  }
  asm volatile("" ::: "memory");
  bf16x8 Qf[2][8];
  #pragma unroll
  for(int qn=0; qn<2; qn++)
    #pragma unroll
    for(int kk=0; kk<8; kk++)
      Qf[qn][kk] = ld8(Qw + (qn*16 + l15)*264 + kk*32 + g*8);
  __syncthreads();

  const float bkv0 = bk[wid*32 + l15], bkv1 = bk[wid*32 + 16 + l15];
  float bvv[2][4];
  #pragma unroll
  for(int m=0; m<2; m++)
    #pragma unroll
    for(int r=0; r<4; r++)
      bvv[m][r] = bv[wid*32 + m*16 + g*4 + r];

  float mr0 = -1e30f, mr1 = -1e30f, lr0 = 0.f, lr1 = 0.f;
  f32x4 Ot[16][2];
  const f32x4 zf = {0,0,0,0};
  #pragma unroll
  for(int i=0;i<16;i++){ Ot[i][0]=zf; Ot[i][1]=zf; }

  for(int kt=0; kt<8; kt++){
    const int kr0 = kt*32;
    {
      int row = tid >> 4, c = tid & 15;
      const float* trow = xb + (size_t)(kr0 + row)*16384;
      #pragma unroll
      for(int j=0; j<4; j++){
        int f0 = (c + 16*j)*4;
        const float* p = trow + (f0>>4)*128 + (f0&15);
        f32x4 v = *(const f32x4*)p;
        us16x4 pk; pk[0]=f2b(v[0]); pk[1]=f2b(v[1]); pk[2]=f2b(v[2]); pk[3]=f2b(v[3]);
        st_sw4(slabb, row, f0, pk);
      }
    }
    __syncthreads();
    {
      f32x4 acc[2][2] = {{zf,zf},{zf,zf}};
      #pragma unroll
      for(int kk=0; kk<8; kk++){
        int f0 = kk*32 + g*8;
        bf16x8 a0 = ld_sw8(slabb, l15, f0);
        bf16x8 a1 = ld_sw8(slabb, 16 + l15, f0);
        #pragma unroll
        for(int n=0; n<2; n++){
          bf16x8 wb = ld8(WkT + (size_t)(wid*32 + n*16 + l15)*256 + f0);
          acc[n][0] = mfma16(a0, wb, acc[n][0]);
          acc[n][1] = mfma16(a1, wb, acc[n][1]);
        }
      }
      #pragma unroll
      for(int n=0; n<2; n++){
        float bias = n ? bkv1 : bkv0;
        #pragma unroll
        for(int r=0; r<4; r++){
          st_sw1(kldsb, g*4+r,      wid*32 + n*16 + l15, f2b(acc[n][0][r] + bias));
          st_sw1(kldsb, 16+g*4+r,   wid*32 + n*16 + l15, f2b(acc[n][1][r] + bias));
        }
      }
    }
    {
      f32x4 acc[2][2] = {{zf,zf},{zf,zf}};
      #pragma unroll
      for(int kk=0; kk<8; kk++){
        int f0 = kk*32 + g*8;
        bf16x8 b0 = ld_sw8(slabb, l15, f0);
        bf16x8 b1 = ld_sw8(slabb, 16 + l15, f0);
        #pragma unroll
        for(int fm=0; fm<2; fm++){
          bf16x8 wa = ld8(WvT + (size_t)(wid*32 + fm*16 + l15)*256 + f0);
          acc[fm][0] = mfma16(wa, b0, acc[fm][0]);
          acc[fm][1] = mfma16(wa, b1, acc[fm][1]);
        }
      }
      #pragma unroll
      for(int fm=0; fm<2; fm++)
        #pragma unroll
        for(int n=0; n<2; n++)
          #pragma unroll
          for(int r=0; r<4; r++){
            int f = wid*32 + fm*16 + g*4 + r;
            Vt[f*40 + n*16 + l15] = f2b(acc[fm][n][r] + bvv[fm][r]);
          }
    }
    __syncthreads();
    f32x4 st[2][2] = {{zf,zf},{zf,zf}};
    #pragma unroll
    for(int kk=0; kk<8; kk++){
      int f0 = kk*32 + g*8;
      bf16x8 k0 = ld_sw8(kldsb, l15, f0);
      bf16x8 k1 = ld_sw8(kldsb, 16 + l15, f0);
      st[0][0] = mfma16(k0, Qf[0][kk], st[0][0]);
      st[0][1] = mfma16(k0, Qf[1][kk], st[0][1]);
      st[1][0] = mfma16(k1, Qf[0][kk], st[1][0]);
      st[1][1] = mfma16(k1, Qf[1][kk], st[1][1]);
    }
    #pragma unroll
    for(int mi=0; mi<2; mi++)
      #pragma unroll
      for(int qn=0; qn<2; qn++)
        #pragma unroll
        for(int r=0; r<4; r++) st[mi][qn][r] *= 0.0625f;
    float tm0 = st[0][0][0], tm1 = st[0][1][0];
    #pragma unroll
    for(int mi=0; mi<2; mi++)
      #pragma unroll
      for(int r=0; r<4; r++){
        tm0 = fmaxf(tm0, st[mi][0][r]);
        tm1 = fmaxf(tm1, st[mi][1][r]);
      }
    tm0 = fmaxf(tm0, __shfl_xor(tm0, 16)); tm0 = fmaxf(tm0, __shfl_xor(tm0, 32));
    tm1 = fmaxf(tm1, __shfl_xor(tm1, 16)); tm1 = fmaxf(tm1, __shfl_xor(tm1, 32));
    float mn0 = fmaxf(mr0, tm0), mn1 = fmaxf(mr1, tm1);
    float c0 = __expf(mr0 - mn0), c1 = __expf(mr1 - mn1);
    float ts0 = 0.f, ts1 = 0.f;
    #pragma unroll
    for(int mi=0; mi<2; mi++)
      #pragma unroll
      for(int r=0; r<4; r++){
        float p0 = __expf(st[mi][0][r] - mn0); st[mi][0][r] = p0; ts0 += p0;
        float p1 = __expf(st[mi][1][r] - mn1); st[mi][1][r] = p1; ts1 += p1;
      }
    ts0 += __shfl_xor(ts0, 16); ts0 += __shfl_xor(ts0, 32);
    ts1 += __shfl_xor(ts1, 16); ts1 += __shfl_xor(ts1, 32);
    lr0 = lr0*c0 + ts0;  lr1 = lr1*c1 + ts1;  mr0 = mn0;  mr1 = mn1;
    #pragma unroll
    for(int i=0;i<16;i++){
      #pragma unroll
      for(int r=0;r<4;r++){ Ot[i][0][r] *= c0; Ot[i][1][r] *= c1; }
    }
    #pragma unroll
    for(int qn=0; qn<2; qn++)
      #pragma unroll
      for(int mi=0; mi<2; mi++)
        #pragma unroll
        for(int rp=0; rp<2; rp++){
          us16x2 pk;
          pk[0] = f2b(st[mi][qn][rp*2]);
          pk[1] = f2b(st[mi][qn][rp*2+1]);
          *(us16x2*)((char*)Psw + (qn*16 + l15)*80 + (mi*16 + g*4 + rp*2)*2) = pk;
        }
    asm volatile("" ::: "memory");
    bf16x8 pb0 = ld8(Psw + l15*40 + g*8);
    bf16x8 pb1 = ld8(Psw + (16 + l15)*40 + g*8);
    #pragma unroll
    for(int fm=0; fm<16; fm++){
      bf16x8 va = ld8(Vt + (fm*16 + l15)*40 + g*8);
      Ot[fm][0] = mfma16(va, pb0, Ot[fm][0]);
      Ot[fm][1] = mfma16(va, pb1, Ot[fm][1]);
    }
    __syncthreads();
  }

  float inv0 = 1.f/lr0, inv1 = 1.f/lr1;
  #pragma unroll
  for(int fm=0; fm<16; fm++)
    #pragma unroll
    for(int rp=0; rp<2; rp++){
      us16x2 p0, p1;
      p0[0]=f2b(Ot[fm][0][rp*2]*inv0);   p0[1]=f2b(Ot[fm][0][rp*2+1]*inv0);
      p1[0]=f2b(Ot[fm][1][rp*2]*inv1);   p1[1]=f2b(Ot[fm][1][rp*2+1]*inv1);
      *(us16x2*)((char*)Qw + l15*528      + (fm*16 + g*4 + rp*2)*2) = p0;
      *(us16x2*)((char*)Qw + (16+l15)*528 + (fm*16 + g*4 + rp*2)*2) = p1;
    }
  asm volatile("" ::: "memory");
  bf16x8 Of[2][8];
  #pragma unroll
  for(int qm=0; qm<2; qm++)
    #pragma unroll
    for(int kk=0; kk<8; kk++)
      Of[qm][kk] = ld8(Qw + (qm*16 + l15)*264 + kk*32 + g*8);
  for(int n0=0; n0<16; n0++){
    f32x4 a0 = {0,0,0,0}, a1 = {0,0,0,0};
    const us16* wrow = WoT + (size_t)(n0*16 + l15)*256;
    #pragma unroll
    for(int kk=0; kk<8; kk++){
      bf16x8 wb = ld8(wrow + kk*32 + g*8);
      a0 = mfma16(Of[0][kk], wb, a0);
      a1 = mfma16(Of[1][kk], wb, a1);
    }
    float bias = bo[n0*16 + l15];
    #pragma unroll
    for(int r=0; r<4; r++){
      yb[(size_t)(r0 + g*4 + r)*16384      + n0*128 + l15] = a0[r] + bias;
      yb[(size_t)(r0 + 16 + g*4 + r)*16384 + n0*128 + l15] = a1[r] + bias;
    }
  }
}

extern "C" void kernel_launch(void* const* d_in, const int* in_sizes, int n_in,
                              void* d_out, int out_size, void* d_ws, size_t ws_size,
                              hipStream_t stream)
{
  const float* x   = (const float*)d_in[0];
  const float* Wq  = (const float*)d_in[1];
  const float* bq  = (const float*)d_in[2];
  const float* Wk  = (const float*)d_in[3];
  const float* bk  = (const float*)d_in[4];
  const float* Wv  = (const float*)d_in[5];
  const float* bv  = (const float*)d_in[6];
  const float* Wo  = (const float*)d_in[7];
  const float* bo  = (const float*)d_in[8];
  const float* W1  = (const float*)d_in[9];
  const float* b1  = (const float*)d_in[10];
  const float* W2  = (const float*)d_in[11];
  const float* b2  = (const float*)d_in[12];
  const float* g1  = (const float*)d_in[13];
  const float* be1 = (const float*)d_in[14];
  const float* g2  = (const float*)d_in[15];
  const float* be2 = (const float*)d_in[16];
  float* out = (float*)d_out;
  char* ws = (char*)d_ws;

  const size_t KVBYTES = 134217728ull;            // 512 slots * 256 KB
  const size_t QBYTES  = 67108864ull;             // 512 slots * 128 KB
  const size_t NEED_B  = KVBYTES + 1572864ull;
  const size_t NEED_A  = KVBYTES + QBYTES + 1572864ull;

  if(ws_size >= NEED_A){
    char* Qimg  = ws + KVBYTES;
    char* wbase = ws + KVBYTES + QBYTES;
    us16* WqT = (us16*)(wbase);
    us16* WkT = (us16*)(wbase + 131072);
    us16* WvT = (us16*)(wbase + 262144);
    us16* WoT = (us16*)(wbase + 393216);
    us16* W1T = (us16*)(wbase + 524288);
    us16* W2T = (us16*)(wbase + 1048576);

    prep_w<<<dim3(256),  dim3(256), 0, stream>>>(Wq, WqT, 256, 256, 8);
    prep_w<<<dim3(256),  dim3(256), 0, stream>>>(Wk, WkT, 256, 256, 8);
    prep_w<<<dim3(256),  dim3(256), 0, stream>>>(Wv, WvT, 256, 256, 8);
    prep_w<<<dim3(256),  dim3(256), 0, stream>>>(Wo, WoT, 256, 256, 8);
    prep_w<<<dim3(1024), dim3(256), 0, stream>>>(W1, W1T, 256, 1024, 10);
    prep_w<<<dim3(1024), dim3(256), 0, stream>>>(W2, W2T, 1024, 256, 8);

    qkv_win<<<dim3(1024), dim3(256), 0, stream>>>(x, WqT, WkT, WvT, bq, bk, bv,
                                                  Qimg, ws);
    attn_hyb2<<<dim3(512), dim3(512), 0, stream>>>(Qimg, ws, WoT, bo, out);
    ffn_ln3s<<<dim3(2048), dim3(512), 0, stream>>>(out, W1T, W2T, b1, b2,
                                                   g1, be1, g2, be2);
  } else if(ws_size >= NEED_B){
    char* wbase = ws + KVBYTES;
    us16* WqT = (us16*)(wbase);
    us16* WkT = (us16*)(wbase + 131072);
    us16* WvT = (us16*)(wbase + 262144);
    us16* WoT = (us16*)(wbase + 393216);
    us16* W1T = (us16*)(wbase + 524288);
    us16* W2T = (us16*)(wbase + 1048576);

    prep_w<<<dim3(256),  dim3(256), 0, stream>>>(Wq, WqT, 256, 256, 8);
    prep_w<<<dim3(256),  dim3(256), 0, stream>>>(Wk, WkT, 256, 256, 8);
    prep_w<<<dim3(256),  dim3(256), 0, stream>>>(Wv, WvT, 256, 256, 8);
    prep_w<<<dim3(256),  dim3(256), 0, stream>>>(Wo, WoT, 256, 256, 8);
    prep_w<<<dim3(1024), dim3(256), 0, stream>>>(W1, W1T, 256, 1024, 10);
    prep_w<<<dim3(1024), dim3(256), 0, stream>>>(W2, W2T, 1024, 256, 8);

    kv_win<<<dim3(1024), dim3(256), 0, stream>>>(x, WkT, WvT, bk, bv, ws);
    attn_hyb<<<dim3(512), dim3(512), 0, stream>>>(x, WqT, bq, ws, WoT, bo, out);
    ffn_ln<<<dim3(2048), dim3(512), 0, stream>>>(out, W1T, W2T, b1, b2,
                                                 g1, be1, g2, be2);
  } else {
    us16* WqT = (us16*)(ws);
    us16* WkT = (us16*)(ws + 131072);
    us16* WvT = (us16*)(ws + 262144);
    us16* WoT = (us16*)(ws + 393216);
    us16* W1T = (us16*)(ws + 524288);
    us16* W2T = (us16*)(ws + 1048576);

    prep_w<<<dim3(256),  dim3(256), 0, stream>>>(Wq, WqT, 256, 256, 8);
    prep_w<<<dim3(256),  dim3(256), 0, stream>>>(Wk, WkT, 256, 256, 8);
    prep_w<<<dim3(256),  dim3(256), 0, stream>>>(Wv, WvT, 256, 256, 8);
    prep_w<<<dim3(256),  dim3(256), 0, stream>>>(Wo, WoT, 256, 256, 8);
    prep_w<<<dim3(1024), dim3(256), 0, stream>>>(W1, W1T, 256, 1024, 10);
    prep_w<<<dim3(1024), dim3(256), 0, stream>>>(W2, W2T, 1024, 256, 8);

    attn_win<<<dim3(512), dim3(512), 0, stream>>>(x, WqT, WkT, WvT, WoT,
                                                  bq, bk, bv, bo, out);
    ffn_ln<<<dim3(2048), dim3(512), 0, stream>>>(out, W1T, W2T, b1, b2,
                                                 g1, be1, g2, be2);
  }
}